// Round 11
// baseline (173.869 us; speedup 1.0000x reference)
//
#include <hip/hip_runtime.h>

typedef short s8v __attribute__((ext_vector_type(8)));
typedef float f4v __attribute__((ext_vector_type(4)));

__device__ __forceinline__ unsigned short f2bf(float f) {
  unsigned u = __float_as_uint(f);
  u = (u + 0x7fffu + ((u >> 16) & 1u)) >> 16;
  return (unsigned short)u;
}
__device__ __forceinline__ float bf2f(unsigned short s) {
  return __uint_as_float(((unsigned)s) << 16);
}

// ---------------------------------------------------------------------------
// Packed-weight region P (ushort offsets):
//   pWis  [0,16384)     pWos0 [16384,24576)  pWos1 [24576,32768)
//   pWo0  [32768,40960) pWo1  [40960,45056)  pW12  [45056,53248)
// Fragment order: P[((kc*(NC/16)+ct)*64+lane)*8+j] =
//                 bf16( W[kc*32+(lane>>4)*8+j][ct*16+(lane&15)] )
// ---------------------------------------------------------------------------
__device__ __forceinline__ void pack_one(const float* __restrict__ W,
                                         unsigned short* __restrict__ P,
                                         int NC, int t) {
  const int lane = t & 63;
  const int ct = (t >> 6) % (NC / 16);
  const int kc = (t >> 6) / (NC / 16);
  const int col = ct * 16 + (lane & 15);
  const int krow = kc * 32 + (lane >> 4) * 8;
  unsigned short tmp[8];
#pragma unroll
  for (int j = 0; j < 8; ++j) tmp[j] = f2bf(W[(krow + j) * NC + col]);
  uint4 o;
  o.x = (unsigned)tmp[0] | ((unsigned)tmp[1] << 16);
  o.y = (unsigned)tmp[2] | ((unsigned)tmp[3] << 16);
  o.z = (unsigned)tmp[4] | ((unsigned)tmp[5] << 16);
  o.w = (unsigned)tmp[6] | ((unsigned)tmp[7] << 16);
  reinterpret_cast<uint4*>(P)[t] = o;
}

// ---------------------------------------------------------------------------
// Mega-prep (all mutually independent):
//   blocks [0, cvtB)           : cvt x_self f32 -> bf16 S1
//   blocks [cvtB, cvtB+zeroB)  : zero deg
//   blocks [cvtB+zeroB, +27)   : pack weights (incl. on-the-fly W12, bvec)
// ---------------------------------------------------------------------------
__global__ __launch_bounds__(256) void prep_kernel(
    const float* __restrict__ x, unsigned short* __restrict__ S1,
    int* __restrict__ deg, const float* __restrict__ Wis,
    const float* __restrict__ Wos, const float* __restrict__ Wo,
    const float* __restrict__ Wg1, const float* __restrict__ Wg2,
    const float* __restrict__ bg1, unsigned short* __restrict__ P,
    float* __restrict__ bvec, int cvtB, int zeroB, int N) {
  const int blk = blockIdx.x;
  const int tid = threadIdx.x;
  if (blk < cvtB) {
    const int i = blk * 256 + tid;  // n4 = N*32 guaranteed multiple of 256? 40000*32/256=5000 exact
    const float4 v = reinterpret_cast<const float4*>(x)[i];
    ushort4 o;
    o.x = f2bf(v.x); o.y = f2bf(v.y); o.z = f2bf(v.z); o.w = f2bf(v.w);
    reinterpret_cast<ushort4*>(S1)[i] = o;
    return;
  }
  const int b1 = blk - cvtB;
  if (b1 < zeroB) {
    const int i = b1 * 256 + tid;
    if (i < N) deg[i] = 0;
    return;
  }
  const int b = b1 - zeroB;  // 0..26
  if (b < 8) {
    pack_one(Wis, P + 0, 128, b * 256 + tid);
  } else if (b < 12) {
    pack_one(Wos, P + 16384, 64, (b - 8) * 256 + tid);
  } else if (b < 16) {
    pack_one(Wos + 128 * 64, P + 24576, 64, (b - 12) * 256 + tid);
  } else if (b < 20) {
    pack_one(Wo, P + 32768, 64, (b - 16) * 256 + tid);
  } else if (b < 22) {
    pack_one(Wo + 128 * 64, P + 40960, 64, (b - 20) * 256 + tid);
  } else if (b < 26) {
    // W12 = Wg1(128x128) @ Wg2(128x64), packed on the fly
    const int t = (b - 22) * 256 + tid;
    const int lane = t & 63;
    const int ct = (t >> 6) % 4;
    const int kc = (t >> 6) / 4;
    const int col = ct * 16 + (lane & 15);
    const int krow = kc * 32 + (lane >> 4) * 8;
    unsigned short tmp[8];
#pragma unroll
    for (int j = 0; j < 8; ++j) {
      float acc = 0.f;
      for (int k = 0; k < 128; ++k)
        acc = fmaf(Wg1[(krow + j) * 128 + k], Wg2[k * 64 + col], acc);
      tmp[j] = f2bf(acc);
    }
    uint4 o;
    o.x = (unsigned)tmp[0] | ((unsigned)tmp[1] << 16);
    o.y = (unsigned)tmp[2] | ((unsigned)tmp[3] << 16);
    o.z = (unsigned)tmp[4] | ((unsigned)tmp[5] << 16);
    o.w = (unsigned)tmp[6] | ((unsigned)tmp[7] << 16);
    reinterpret_cast<uint4*>(P + 45056)[t] = o;
  } else if (tid < 64) {
    float acc = 0.f;
    for (int k = 0; k < 128; ++k) acc = fmaf(bg1[k], Wg2[k * 64 + tid], acc);
    bvec[tid] = acc;
  }
}

// ---------------------------------------------------------------------------
// MFMA GEMM: C = A1[M x K1] @ B1 (+ A2[M x K2] @ B2) + bias, optional relu.
// A1 bf16 row-major, or f32 row-major if A1F32 (converted in-register).
// B* pre-packed fragment-order bf16 staged in LDS. M % 64 == 0.
// ---------------------------------------------------------------------------
template <int K1, int K2, int NC, bool RELU, bool OUT_BF16, bool A1F32>
__global__ __launch_bounds__(256) void mfma_gemm_kernel(
    const void* __restrict__ A1v, const unsigned short* __restrict__ A2,
    const unsigned short* __restrict__ P1, const unsigned short* __restrict__ P2,
    const float* __restrict__ bias, void* __restrict__ Cout) {
  constexpr int NT = NC / 16;
  constexpr int KC1 = K1 / 32;
  constexpr int KC2 = (K2 > 0) ? (K2 / 32) : 1;
  __shared__ unsigned short Bs[(K1 + K2) * NC];

  {
    uint4* d = reinterpret_cast<uint4*>(Bs);
    constexpr int n1 = K1 * NC / 8;
    const uint4* s1 = reinterpret_cast<const uint4*>(P1);
    for (int i = threadIdx.x; i < n1; i += 256) d[i] = s1[i];
    if constexpr (K2 > 0) {
      constexpr int n2 = K2 * NC / 8;
      const uint4* s2 = reinterpret_cast<const uint4*>(P2);
      for (int i = threadIdx.x; i < n2; i += 256) d[n1 + i] = s2[i];
    }
  }

  const int wave = threadIdx.x >> 6;
  const int lane = threadIdx.x & 63;
  const int row0 = blockIdx.x * 64 + wave * 16;
  const int arow = row0 + (lane & 15);
  const int koff = (lane >> 4) * 8;

  s8v a1[KC1];
  if constexpr (A1F32) {
    const float* A1f = (const float*)A1v;
#pragma unroll
    for (int kc = 0; kc < KC1; ++kc) {
      const float4 f0 = *reinterpret_cast<const float4*>(
          A1f + (long long)arow * K1 + kc * 32 + koff);
      const float4 f1 = *reinterpret_cast<const float4*>(
          A1f + (long long)arow * K1 + kc * 32 + koff + 4);
      s8v r;
      r[0] = (short)f2bf(f0.x); r[1] = (short)f2bf(f0.y);
      r[2] = (short)f2bf(f0.z); r[3] = (short)f2bf(f0.w);
      r[4] = (short)f2bf(f1.x); r[5] = (short)f2bf(f1.y);
      r[6] = (short)f2bf(f1.z); r[7] = (short)f2bf(f1.w);
      a1[kc] = r;
    }
  } else {
    const unsigned short* A1b = (const unsigned short*)A1v;
#pragma unroll
    for (int kc = 0; kc < KC1; ++kc)
      a1[kc] = *reinterpret_cast<const s8v*>(A1b + (long long)arow * K1 +
                                             kc * 32 + koff);
  }
  s8v a2[KC2];
  if constexpr (K2 > 0) {
#pragma unroll
    for (int kc = 0; kc < K2 / 32; ++kc)
      a2[kc] = *reinterpret_cast<const s8v*>(A2 + (long long)arow * K2 +
                                             kc * 32 + koff);
  }

  __syncthreads();

  f4v acc[NT] = {};
#pragma unroll
  for (int kc = 0; kc < KC1; ++kc) {
#pragma unroll
    for (int ct = 0; ct < NT; ++ct) {
      const s8v b =
          *reinterpret_cast<const s8v*>(&Bs[((kc * NT + ct) * 64 + lane) * 8]);
      acc[ct] = __builtin_amdgcn_mfma_f32_16x16x32_bf16(a1[kc], b, acc[ct], 0, 0, 0);
    }
  }
  if constexpr (K2 > 0) {
#pragma unroll
    for (int kc = 0; kc < K2 / 32; ++kc) {
#pragma unroll
      for (int ct = 0; ct < NT; ++ct) {
        const s8v b = *reinterpret_cast<const s8v*>(
            &Bs[(((KC1 + kc) * NT + ct) * 64 + lane) * 8]);
        acc[ct] = __builtin_amdgcn_mfma_f32_16x16x32_bf16(a2[kc], b, acc[ct], 0, 0, 0);
      }
    }
  }

  const int crow0 = row0 + (lane >> 4) * 4;
  const int ccol = lane & 15;
#pragma unroll
  for (int ct = 0; ct < NT; ++ct) {
    const int col = ct * 16 + ccol;
    const float bv = bias ? bias[col] : 0.f;
#pragma unroll
    for (int r = 0; r < 4; ++r) {
      float v = acc[ct][r] + bv;
      if (RELU) v = fmaxf(v, 0.f);
      const long long idx = (long long)(crow0 + r) * NC + col;
      if (OUT_BF16)
        ((unsigned short*)Cout)[idx] = f2bf(v);
      else
        ((float*)Cout)[idx] = v;
    }
  }
}

// ---------------------------------------------------------------------------
// CSR build
// ---------------------------------------------------------------------------
__global__ __launch_bounds__(256) void deg_kernel(
    const int* __restrict__ cols, int* __restrict__ deg, int E) {
  const int i = blockIdx.x * 256 + threadIdx.x;
  if (i < E) atomicAdd(&deg[cols[i]], 1);
}

__global__ __launch_bounds__(1024) void scan1_kernel(
    const int* __restrict__ deg, int* __restrict__ off, int* __restrict__ part,
    float* __restrict__ dis, int N) {
  __shared__ int s[1024];
  const int tid = threadIdx.x;
  const int i = blockIdx.x * 1024 + tid;
  const int v = (i < N) ? deg[i] : 0;
  if (i < N) dis[i] = rsqrtf((float)v + 1.0f);
  s[tid] = v;
  __syncthreads();
  for (int o = 1; o < 1024; o <<= 1) {
    const int t = (tid >= o) ? s[tid - o] : 0;
    __syncthreads();
    s[tid] += t;
    __syncthreads();
  }
  if (i < N) off[i] = s[tid] - v;
  if (tid == 1023) part[blockIdx.x] = s[1023];
}

__global__ __launch_bounds__(1024) void scan3_kernel(
    int* __restrict__ off, const int* __restrict__ part, int N) {
  __shared__ int pp;
  if (threadIdx.x < 64) {
    int v = (threadIdx.x < blockIdx.x) ? part[threadIdx.x] : 0;
#pragma unroll
    for (int o = 32; o > 0; o >>= 1) v += __shfl_down(v, o, 64);
    if (threadIdx.x == 0) pp = v;
  }
  __syncthreads();
  const int i = blockIdx.x * 1024 + threadIdx.x;
  if (i < N) off[i] += pp;
}

// csr[pos] = (src, w = dis[src]*dis[dst]).  Afterwards off[c] = END of seg c.
__global__ __launch_bounds__(256) void fill_kernel(
    const int* __restrict__ rows, const int* __restrict__ cols,
    int* __restrict__ off, const float* __restrict__ dis,
    int2* __restrict__ csr, int E) {
  const int i = blockIdx.x * 256 + threadIdx.x;
  if (i < E) {
    const int c = cols[i];
    const int r = rows[i];
    const int pos = atomicAdd(&off[c], 1);
    int2 e;
    e.x = r;
    e.y = __float_as_int(dis[r] * dis[c]);
    csr[pos] = e;
  }
}

// ---------------------------------------------------------------------------
// D=64 CSR gather, 4 nodes per wave (16-lane groups, ushort4/lane), 4-unroll.
// Pass A: out[n]=A·h (bf16), s_out[n]=Σw+dn².  Pass B: + s_in*bvec + bias.
// ---------------------------------------------------------------------------
template <bool PASS_B>
__global__ __launch_bounds__(256) void gather64_kernel(
    const unsigned short* __restrict__ h, const int2* __restrict__ csr,
    const int* __restrict__ off, const float* __restrict__ dis,
    float* __restrict__ s_out, const float* __restrict__ s_in,
    const float* __restrict__ bvec, const float* __restrict__ bias,
    unsigned short* __restrict__ out, int N) {
  const int wid = (blockIdx.x * 256 + threadIdx.x) >> 6;
  const int lane = threadIdx.x & 63;
  const int grp = lane >> 4;
  const int sl = lane & 15;
  const int stride = gridDim.x * 16;

  float bb0 = 0.f, bb1 = 0.f, bb2 = 0.f, bb3 = 0.f;
  float bv0 = 0.f, bv1 = 0.f, bv2 = 0.f, bv3 = 0.f;
  if constexpr (PASS_B) {
    const float4 b4 = *reinterpret_cast<const float4*>(bias + sl * 4);
    bb0 = b4.x; bb1 = b4.y; bb2 = b4.z; bb3 = b4.w;
    const float4 v4 = *reinterpret_cast<const float4*>(bvec + sl * 4);
    bv0 = v4.x; bv1 = v4.y; bv2 = v4.z; bv3 = v4.w;
  }

  for (int n = wid * 4 + grp; n < N; n += stride) {
    const float dn = dis[n];
    const float dn2 = dn * dn;
    const ushort4 hv =
        *reinterpret_cast<const ushort4*>(h + (long long)n * 64 + sl * 4);
    float a0 = bf2f(hv.x) * dn2, a1 = bf2f(hv.y) * dn2;
    float a2 = bf2f(hv.z) * dn2, a3 = bf2f(hv.w) * dn2;
    float sw = dn2;
    const int start = (n == 0) ? 0 : off[n - 1];
    const int end = off[n];
    int j = start;
    for (; j + 3 < end; j += 4) {
      const int2 p0 = csr[j], p1 = csr[j + 1], p2 = csr[j + 2], p3 = csr[j + 3];
      const ushort4 u0 =
          *reinterpret_cast<const ushort4*>(h + (long long)p0.x * 64 + sl * 4);
      const ushort4 u1 =
          *reinterpret_cast<const ushort4*>(h + (long long)p1.x * 64 + sl * 4);
      const ushort4 u2 =
          *reinterpret_cast<const ushort4*>(h + (long long)p2.x * 64 + sl * 4);
      const ushort4 u3 =
          *reinterpret_cast<const ushort4*>(h + (long long)p3.x * 64 + sl * 4);
      const float w0 = __int_as_float(p0.y), w1 = __int_as_float(p1.y);
      const float w2 = __int_as_float(p2.y), w3 = __int_as_float(p3.y);
      a0 = fmaf(bf2f(u0.x), w0, a0); a1 = fmaf(bf2f(u0.y), w0, a1);
      a2 = fmaf(bf2f(u0.z), w0, a2); a3 = fmaf(bf2f(u0.w), w0, a3);
      a0 = fmaf(bf2f(u1.x), w1, a0); a1 = fmaf(bf2f(u1.y), w1, a1);
      a2 = fmaf(bf2f(u1.z), w1, a2); a3 = fmaf(bf2f(u1.w), w1, a3);
      a0 = fmaf(bf2f(u2.x), w2, a0); a1 = fmaf(bf2f(u2.y), w2, a1);
      a2 = fmaf(bf2f(u2.z), w2, a2); a3 = fmaf(bf2f(u2.w), w2, a3);
      a0 = fmaf(bf2f(u3.x), w3, a0); a1 = fmaf(bf2f(u3.y), w3, a1);
      a2 = fmaf(bf2f(u3.z), w3, a2); a3 = fmaf(bf2f(u3.w), w3, a3);
      if constexpr (!PASS_B) sw += (w0 + w1) + (w2 + w3);
    }
    for (; j < end; ++j) {
      const int2 p = csr[j];
      const ushort4 u =
          *reinterpret_cast<const ushort4*>(h + (long long)p.x * 64 + sl * 4);
      const float w = __int_as_float(p.y);
      a0 = fmaf(bf2f(u.x), w, a0); a1 = fmaf(bf2f(u.y), w, a1);
      a2 = fmaf(bf2f(u.z), w, a2); a3 = fmaf(bf2f(u.w), w, a3);
      if constexpr (!PASS_B) sw += w;
    }
    if constexpr (!PASS_B) {
      if (sl == 0) s_out[n] = sw;
      ushort4 o;
      o.x = f2bf(a0); o.y = f2bf(a1); o.z = f2bf(a2); o.w = f2bf(a3);
      *reinterpret_cast<ushort4*>(out + (long long)n * 64 + sl * 4) = o;
    } else {
      const float si = s_in[n];
      ushort4 o;
      o.x = f2bf(fmaf(si, bv0, a0 + bb0));
      o.y = f2bf(fmaf(si, bv1, a1 + bb1));
      o.z = f2bf(fmaf(si, bv2, a2 + bb2));
      o.w = f2bf(fmaf(si, bv3, a3 + bb3));
      *reinterpret_cast<ushort4*>(out + (long long)n * 64 + sl * 4) = o;
    }
  }
}

extern "C" void kernel_launch(void* const* d_in, const int* in_sizes, int n_in,
                              void* d_out, int out_size, void* d_ws,
                              size_t ws_size, hipStream_t stream) {
  const float* x_self = (const float*)d_in[0];
  const float* x_nb = (const float*)d_in[1];
  const int* ei = (const int*)d_in[2];
  const float* Wis = (const float*)d_in[3];
  const float* bis = (const float*)d_in[4];
  const float* Wos = (const float*)d_in[5];
  const float* bos = (const float*)d_in[6];
  const float* Wg1 = (const float*)d_in[7];
  const float* bg1 = (const float*)d_in[8];
  const float* Wg2 = (const float*)d_in[9];
  const float* bg2 = (const float*)d_in[10];
  const float* Wo = (const float*)d_in[11];
  const float* bo = (const float*)d_in[12];

  const int N = in_sizes[0] / 128;
  const int E = (int)(in_sizes[2] / 2);
  const int* rows = ei;
  const int* cols = ei + E;

  float* out1 = (float*)d_out;
  float* out2 = out1 + (long long)N * 64;

  // ws (4B units): dis[N] | deg[N] | off[N+16] | part[64] | s[N] | bvec[64] |
  //   csr int2[E] | S1 bf16[N*128] | S2 bf16[N*128] | S3 bf16[N*64] | P[53248]
  float* dis = (float*)d_ws;
  int* deg = (int*)(dis + N);
  int* off = deg + N;
  int* part = off + N + 16;
  float* s = (float*)(part + 64);
  float* bvec = s + N;
  int2* csr = (int2*)(bvec + 64);
  unsigned short* S1 = (unsigned short*)(csr + E);
  unsigned short* S2 = S1 + (long long)N * 128;
  unsigned short* S3 = S2 + (long long)N * 128;
  unsigned short* P = S3 + (long long)N * 64;
  unsigned short* pWis = P + 0;
  unsigned short* pWos0 = P + 16384;
  unsigned short* pWos1 = P + 24576;
  unsigned short* pWo0 = P + 32768;
  unsigned short* pWo1 = P + 40960;
  unsigned short* pW12 = P + 45056;

  const int NB = (N + 1023) / 1024;
  const int GB = N / 64;          // 625
  const int GGB = (N + 15) / 16;  // 2500: 1 node per 16-lane group

  const int cvtB = (N * 32 + 255) / 256;   // 5000
  const int zeroB = (N + 255) / 256;       // 157

  // --- mega-prep: cvt | zero deg | pack weights (+W12, bvec) ---
  prep_kernel<<<cvtB + zeroB + 27, 256, 0, stream>>>(
      x_self, S1, deg, Wis, Wos, Wo, Wg1, Wg2, bg1, P, bvec, cvtB, zeroB, N);

  // --- CSR build + norms ---
  deg_kernel<<<(E + 255) / 256, 256, 0, stream>>>(cols, deg, E);
  scan1_kernel<<<NB, 1024, 0, stream>>>(deg, off, part, dis, N);
  scan3_kernel<<<NB, 1024, 0, stream>>>(off, part, N);
  fill_kernel<<<(E + 255) / 256, 256, 0, stream>>>(rows, cols, off, dis, csr, E);

  // --- self branch ---
  mfma_gemm_kernel<128, 0, 128, true, true, false>
      <<<GB, 256, 0, stream>>>(S1, nullptr, pWis, nullptr, bis, S2);
  mfma_gemm_kernel<128, 128, 64, false, false, false>
      <<<GB, 256, 0, stream>>>(S1, S2, pWos0, pWos1, bos, out1);

  // --- GCN branch: g2 = A·(A·(X·W12)) + s·(bg1·Wg2) + bg2 ---
  mfma_gemm_kernel<128, 0, 64, false, true, false>
      <<<GB, 256, 0, stream>>>(S1, nullptr, pW12, nullptr, nullptr, S2);
  gather64_kernel<false><<<GGB, 256, 0, stream>>>(
      S2, csr, off, dis, s, nullptr, nullptr, nullptr, S3, N);
  gather64_kernel<true><<<GGB, 256, 0, stream>>>(
      S3, csr, off, dis, nullptr, s, bvec, bg2, S1, N);
  mfma_gemm_kernel<128, 64, 64, false, false, true>
      <<<GB, 256, 0, stream>>>(x_nb, S1, pWo0, pWo1, bo, out2);
}

// Round 12
// 152.827 us; speedup vs baseline: 1.1377x; 1.1377x over previous
//
#include <hip/hip_runtime.h>

typedef short s8v __attribute__((ext_vector_type(8)));
typedef float f4v __attribute__((ext_vector_type(4)));

__device__ __forceinline__ unsigned short f2bf(float f) {
  unsigned u = __float_as_uint(f);
  u = (u + 0x7fffu + ((u >> 16) & 1u)) >> 16;
  return (unsigned short)u;
}
__device__ __forceinline__ float bf2f(unsigned short s) {
  return __uint_as_float(((unsigned)s) << 16);
}

// ---------------------------------------------------------------------------
// Packed-weight region P (ushort offsets):
//   pWis  [0,16384)     pWos0 [16384,24576)  pWos1 [24576,32768)
//   pWo0  [32768,40960) pWo1  [40960,45056)  pW12  [45056,53248)
// Fragment order: P[((kc*(NC/16)+ct)*64+lane)*8+j] =
//                 bf16( W[kc*32+(lane>>4)*8+j][ct*16+(lane&15)] )
// ---------------------------------------------------------------------------
__device__ __forceinline__ void pack_one(const float* __restrict__ W,
                                         unsigned short* __restrict__ P,
                                         int NC, int t) {
  const int lane = t & 63;
  const int ct = (t >> 6) % (NC / 16);
  const int kc = (t >> 6) / (NC / 16);
  const int col = ct * 16 + (lane & 15);
  const int krow = kc * 32 + (lane >> 4) * 8;
  unsigned short tmp[8];
#pragma unroll
  for (int j = 0; j < 8; ++j) tmp[j] = f2bf(W[(krow + j) * NC + col]);
  uint4 o;
  o.x = (unsigned)tmp[0] | ((unsigned)tmp[1] << 16);
  o.y = (unsigned)tmp[2] | ((unsigned)tmp[3] << 16);
  o.z = (unsigned)tmp[4] | ((unsigned)tmp[5] << 16);
  o.w = (unsigned)tmp[6] | ((unsigned)tmp[7] << 16);
  reinterpret_cast<uint4*>(P)[t] = o;
}

// ---------------------------------------------------------------------------
// W12 = Wg1 @ Wg2 computed one element per thread (flat 128-FMA loops, no
// long-tail blocks) and written DIRECTLY in packed fragment order as bf16.
// Mapping for element (i,j): kc=i>>5, lane=((i>>3)&3)*16+(j&15), jj=i&7,
// ct=j>>4  ->  P12[((kc*4+ct)*64+lane)*8+jj]  (row=i, col=j verified).
// Block 32: bvec[j] = bg1 @ Wg2.
// ---------------------------------------------------------------------------
__global__ __launch_bounds__(256) void w12_kernel(
    const float* __restrict__ Wg1, const float* __restrict__ Wg2,
    const float* __restrict__ bg1, unsigned short* __restrict__ P12,
    float* __restrict__ bvec) {
  const int b = blockIdx.x;
  if (b < 32) {
    const int t = b * 256 + threadIdx.x;  // t = i*64 + j
    const int i = t >> 6, j = t & 63;
    float acc = 0.f;
    for (int k = 0; k < 128; ++k)
      acc = fmaf(Wg1[i * 128 + k], Wg2[k * 64 + j], acc);
    const int kc = i >> 5;
    const int lane = ((i >> 3) & 3) * 16 + (j & 15);
    const int jj = i & 7;
    const int ct = j >> 4;
    P12[((kc * 4 + ct) * 64 + lane) * 8 + jj] = f2bf(acc);
  } else if (threadIdx.x < 64) {
    const int j = threadIdx.x;
    float acc = 0.f;
    for (int k = 0; k < 128; ++k) acc = fmaf(bg1[k], Wg2[k * 64 + j], acc);
    bvec[j] = acc;
  }
}

// ---------------------------------------------------------------------------
// Flat prep (no long-tail blocks):
//   blocks [0, cvtB)          : cvt x_self f32 -> bf16 S1
//   blocks [cvtB, cvtB+zeroB) : zero deg
//   + 22 pack blocks          : 8 Wis | 4 Wos0 | 4 Wos1 | 4 Wo0 | 2 Wo1
// ---------------------------------------------------------------------------
__global__ __launch_bounds__(256) void prep_kernel(
    const float* __restrict__ x, unsigned short* __restrict__ S1,
    int* __restrict__ deg, const float* __restrict__ Wis,
    const float* __restrict__ Wos, const float* __restrict__ Wo,
    unsigned short* __restrict__ P, int cvtB, int zeroB, int N) {
  const int blk = blockIdx.x;
  const int tid = threadIdx.x;
  if (blk < cvtB) {
    const int i = blk * 256 + tid;  // N*32 = 1.28M, /256 = 5000 exact
    const float4 v = reinterpret_cast<const float4*>(x)[i];
    ushort4 o;
    o.x = f2bf(v.x); o.y = f2bf(v.y); o.z = f2bf(v.z); o.w = f2bf(v.w);
    reinterpret_cast<ushort4*>(S1)[i] = o;
    return;
  }
  const int b1 = blk - cvtB;
  if (b1 < zeroB) {
    const int i = b1 * 256 + tid;
    if (i < N) deg[i] = 0;
    return;
  }
  const int b = b1 - zeroB;  // 0..21
  if (b < 8)        pack_one(Wis,            P + 0,     128, b * 256 + tid);
  else if (b < 12)  pack_one(Wos,            P + 16384, 64,  (b - 8) * 256 + tid);
  else if (b < 16)  pack_one(Wos + 128 * 64, P + 24576, 64,  (b - 12) * 256 + tid);
  else if (b < 20)  pack_one(Wo,             P + 32768, 64,  (b - 16) * 256 + tid);
  else              pack_one(Wo + 128 * 64,  P + 40960, 64,  (b - 20) * 256 + tid);
}

// ---------------------------------------------------------------------------
// MFMA GEMM: C = A1[M x K1] @ B1 (+ A2[M x K2] @ B2) + bias, optional relu.
// A1 bf16 row-major, or f32 row-major if A1F32 (converted in-register).
// ---------------------------------------------------------------------------
template <int K1, int K2, int NC, bool RELU, bool OUT_BF16, bool A1F32>
__global__ __launch_bounds__(256) void mfma_gemm_kernel(
    const void* __restrict__ A1v, const unsigned short* __restrict__ A2,
    const unsigned short* __restrict__ P1, const unsigned short* __restrict__ P2,
    const float* __restrict__ bias, void* __restrict__ Cout) {
  constexpr int NT = NC / 16;
  constexpr int KC1 = K1 / 32;
  constexpr int KC2 = (K2 > 0) ? (K2 / 32) : 1;
  __shared__ unsigned short Bs[(K1 + K2) * NC];

  {
    uint4* d = reinterpret_cast<uint4*>(Bs);
    constexpr int n1 = K1 * NC / 8;
    const uint4* s1 = reinterpret_cast<const uint4*>(P1);
    for (int i = threadIdx.x; i < n1; i += 256) d[i] = s1[i];
    if constexpr (K2 > 0) {
      constexpr int n2 = K2 * NC / 8;
      const uint4* s2 = reinterpret_cast<const uint4*>(P2);
      for (int i = threadIdx.x; i < n2; i += 256) d[n1 + i] = s2[i];
    }
  }

  const int wave = threadIdx.x >> 6;
  const int lane = threadIdx.x & 63;
  const int row0 = blockIdx.x * 64 + wave * 16;
  const int arow = row0 + (lane & 15);
  const int koff = (lane >> 4) * 8;

  s8v a1[KC1];
  if constexpr (A1F32) {
    const float* A1f = (const float*)A1v;
#pragma unroll
    for (int kc = 0; kc < KC1; ++kc) {
      const float4 f0 = *reinterpret_cast<const float4*>(
          A1f + (long long)arow * K1 + kc * 32 + koff);
      const float4 f1 = *reinterpret_cast<const float4*>(
          A1f + (long long)arow * K1 + kc * 32 + koff + 4);
      s8v r;
      r[0] = (short)f2bf(f0.x); r[1] = (short)f2bf(f0.y);
      r[2] = (short)f2bf(f0.z); r[3] = (short)f2bf(f0.w);
      r[4] = (short)f2bf(f1.x); r[5] = (short)f2bf(f1.y);
      r[6] = (short)f2bf(f1.z); r[7] = (short)f2bf(f1.w);
      a1[kc] = r;
    }
  } else {
    const unsigned short* A1b = (const unsigned short*)A1v;
#pragma unroll
    for (int kc = 0; kc < KC1; ++kc)
      a1[kc] = *reinterpret_cast<const s8v*>(A1b + (long long)arow * K1 +
                                             kc * 32 + koff);
  }
  s8v a2[KC2];
  if constexpr (K2 > 0) {
#pragma unroll
    for (int kc = 0; kc < K2 / 32; ++kc)
      a2[kc] = *reinterpret_cast<const s8v*>(A2 + (long long)arow * K2 +
                                             kc * 32 + koff);
  }

  __syncthreads();

  f4v acc[NT] = {};
#pragma unroll
  for (int kc = 0; kc < KC1; ++kc) {
#pragma unroll
    for (int ct = 0; ct < NT; ++ct) {
      const s8v b =
          *reinterpret_cast<const s8v*>(&Bs[((kc * NT + ct) * 64 + lane) * 8]);
      acc[ct] = __builtin_amdgcn_mfma_f32_16x16x32_bf16(a1[kc], b, acc[ct], 0, 0, 0);
    }
  }
  if constexpr (K2 > 0) {
#pragma unroll
    for (int kc = 0; kc < K2 / 32; ++kc) {
#pragma unroll
      for (int ct = 0; ct < NT; ++ct) {
        const s8v b = *reinterpret_cast<const s8v*>(
            &Bs[(((KC1 + kc) * NT + ct) * 64 + lane) * 8]);
        acc[ct] = __builtin_amdgcn_mfma_f32_16x16x32_bf16(a2[kc], b, acc[ct], 0, 0, 0);
      }
    }
  }

  const int crow0 = row0 + (lane >> 4) * 4;
  const int ccol = lane & 15;
#pragma unroll
  for (int ct = 0; ct < NT; ++ct) {
    const int col = ct * 16 + ccol;
    const float bv = bias ? bias[col] : 0.f;
#pragma unroll
    for (int r = 0; r < 4; ++r) {
      float v = acc[ct][r] + bv;
      if (RELU) v = fmaxf(v, 0.f);
      const long long idx = (long long)(crow0 + r) * NC + col;
      if (OUT_BF16)
        ((unsigned short*)Cout)[idx] = f2bf(v);
      else
        ((float*)Cout)[idx] = v;
    }
  }
}

// ---------------------------------------------------------------------------
// CSR build
// ---------------------------------------------------------------------------
__global__ __launch_bounds__(256) void deg_kernel(
    const int* __restrict__ cols, int* __restrict__ deg, int E) {
  const int i = blockIdx.x * 256 + threadIdx.x;
  if (i < E) atomicAdd(&deg[cols[i]], 1);
}

__global__ __launch_bounds__(1024) void scan1_kernel(
    const int* __restrict__ deg, int* __restrict__ off, int* __restrict__ part,
    float* __restrict__ dis, int N) {
  __shared__ int s[1024];
  const int tid = threadIdx.x;
  const int i = blockIdx.x * 1024 + tid;
  const int v = (i < N) ? deg[i] : 0;
  if (i < N) dis[i] = rsqrtf((float)v + 1.0f);
  s[tid] = v;
  __syncthreads();
  for (int o = 1; o < 1024; o <<= 1) {
    const int t = (tid >= o) ? s[tid - o] : 0;
    __syncthreads();
    s[tid] += t;
    __syncthreads();
  }
  if (i < N) off[i] = s[tid] - v;
  if (tid == 1023) part[blockIdx.x] = s[1023];
}

__global__ __launch_bounds__(1024) void scan3_kernel(
    int* __restrict__ off, const int* __restrict__ part, int N) {
  __shared__ int pp;
  if (threadIdx.x < 64) {
    int v = (threadIdx.x < blockIdx.x) ? part[threadIdx.x] : 0;
#pragma unroll
    for (int o = 32; o > 0; o >>= 1) v += __shfl_down(v, o, 64);
    if (threadIdx.x == 0) pp = v;
  }
  __syncthreads();
  const int i = blockIdx.x * 1024 + threadIdx.x;
  if (i < N) off[i] += pp;
}

// csr[pos] = (src, w = dis[src]*dis[dst]).  Afterwards off[c] = END of seg c.
__global__ __launch_bounds__(256) void fill_kernel(
    const int* __restrict__ rows, const int* __restrict__ cols,
    int* __restrict__ off, const float* __restrict__ dis,
    int2* __restrict__ csr, int E) {
  const int i = blockIdx.x * 256 + threadIdx.x;
  if (i < E) {
    const int c = cols[i];
    const int r = rows[i];
    const int pos = atomicAdd(&off[c], 1);
    int2 e;
    e.x = r;
    e.y = __float_as_int(dis[r] * dis[c]);
    csr[pos] = e;
  }
}

// ---------------------------------------------------------------------------
// D=64 CSR gather, 4 nodes per wave (16-lane groups, ushort4/lane), 4-unroll.
// Pass A: out[n]=A·h (bf16), s_out[n]=Σw+dn².  Pass B: + s_in*bvec + bias.
// ---------------------------------------------------------------------------
template <bool PASS_B>
__global__ __launch_bounds__(256) void gather64_kernel(
    const unsigned short* __restrict__ h, const int2* __restrict__ csr,
    const int* __restrict__ off, const float* __restrict__ dis,
    float* __restrict__ s_out, const float* __restrict__ s_in,
    const float* __restrict__ bvec, const float* __restrict__ bias,
    unsigned short* __restrict__ out, int N) {
  const int wid = (blockIdx.x * 256 + threadIdx.x) >> 6;
  const int lane = threadIdx.x & 63;
  const int grp = lane >> 4;
  const int sl = lane & 15;
  const int stride = gridDim.x * 16;

  float bb0 = 0.f, bb1 = 0.f, bb2 = 0.f, bb3 = 0.f;
  float bv0 = 0.f, bv1 = 0.f, bv2 = 0.f, bv3 = 0.f;
  if constexpr (PASS_B) {
    const float4 b4 = *reinterpret_cast<const float4*>(bias + sl * 4);
    bb0 = b4.x; bb1 = b4.y; bb2 = b4.z; bb3 = b4.w;
    const float4 v4 = *reinterpret_cast<const float4*>(bvec + sl * 4);
    bv0 = v4.x; bv1 = v4.y; bv2 = v4.z; bv3 = v4.w;
  }

  for (int n = wid * 4 + grp; n < N; n += stride) {
    const float dn = dis[n];
    const float dn2 = dn * dn;
    const ushort4 hv =
        *reinterpret_cast<const ushort4*>(h + (long long)n * 64 + sl * 4);
    float a0 = bf2f(hv.x) * dn2, a1 = bf2f(hv.y) * dn2;
    float a2 = bf2f(hv.z) * dn2, a3 = bf2f(hv.w) * dn2;
    float sw = dn2;
    const int start = (n == 0) ? 0 : off[n - 1];
    const int end = off[n];
    int j = start;
    for (; j + 3 < end; j += 4) {
      const int2 p0 = csr[j], p1 = csr[j + 1], p2 = csr[j + 2], p3 = csr[j + 3];
      const ushort4 u0 =
          *reinterpret_cast<const ushort4*>(h + (long long)p0.x * 64 + sl * 4);
      const ushort4 u1 =
          *reinterpret_cast<const ushort4*>(h + (long long)p1.x * 64 + sl * 4);
      const ushort4 u2 =
          *reinterpret_cast<const ushort4*>(h + (long long)p2.x * 64 + sl * 4);
      const ushort4 u3 =
          *reinterpret_cast<const ushort4*>(h + (long long)p3.x * 64 + sl * 4);
      const float w0 = __int_as_float(p0.y), w1 = __int_as_float(p1.y);
      const float w2 = __int_as_float(p2.y), w3 = __int_as_float(p3.y);
      a0 = fmaf(bf2f(u0.x), w0, a0); a1 = fmaf(bf2f(u0.y), w0, a1);
      a2 = fmaf(bf2f(u0.z), w0, a2); a3 = fmaf(bf2f(u0.w), w0, a3);
      a0 = fmaf(bf2f(u1.x), w1, a0); a1 = fmaf(bf2f(u1.y), w1, a1);
      a2 = fmaf(bf2f(u1.z), w1, a2); a3 = fmaf(bf2f(u1.w), w1, a3);
      a0 = fmaf(bf2f(u2.x), w2, a0); a1 = fmaf(bf2f(u2.y), w2, a1);
      a2 = fmaf(bf2f(u2.z), w2, a2); a3 = fmaf(bf2f(u2.w), w2, a3);
      a0 = fmaf(bf2f(u3.x), w3, a0); a1 = fmaf(bf2f(u3.y), w3, a1);
      a2 = fmaf(bf2f(u3.z), w3, a2); a3 = fmaf(bf2f(u3.w), w3, a3);
      if constexpr (!PASS_B) sw += (w0 + w1) + (w2 + w3);
    }
    for (; j < end; ++j) {
      const int2 p = csr[j];
      const ushort4 u =
          *reinterpret_cast<const ushort4*>(h + (long long)p.x * 64 + sl * 4);
      const float w = __int_as_float(p.y);
      a0 = fmaf(bf2f(u.x), w, a0); a1 = fmaf(bf2f(u.y), w, a1);
      a2 = fmaf(bf2f(u.z), w, a2); a3 = fmaf(bf2f(u.w), w, a3);
      if constexpr (!PASS_B) sw += w;
    }
    if constexpr (!PASS_B) {
      if (sl == 0) s_out[n] = sw;
      ushort4 o;
      o.x = f2bf(a0); o.y = f2bf(a1); o.z = f2bf(a2); o.w = f2bf(a3);
      *reinterpret_cast<ushort4*>(out + (long long)n * 64 + sl * 4) = o;
    } else {
      const float si = s_in[n];
      ushort4 o;
      o.x = f2bf(fmaf(si, bv0, a0 + bb0));
      o.y = f2bf(fmaf(si, bv1, a1 + bb1));
      o.z = f2bf(fmaf(si, bv2, a2 + bb2));
      o.w = f2bf(fmaf(si, bv3, a3 + bb3));
      *reinterpret_cast<ushort4*>(out + (long long)n * 64 + sl * 4) = o;
    }
  }
}

extern "C" void kernel_launch(void* const* d_in, const int* in_sizes, int n_in,
                              void* d_out, int out_size, void* d_ws,
                              size_t ws_size, hipStream_t stream) {
  const float* x_self = (const float*)d_in[0];
  const float* x_nb = (const float*)d_in[1];
  const int* ei = (const int*)d_in[2];
  const float* Wis = (const float*)d_in[3];
  const float* bis = (const float*)d_in[4];
  const float* Wos = (const float*)d_in[5];
  const float* bos = (const float*)d_in[6];
  const float* Wg1 = (const float*)d_in[7];
  const float* bg1 = (const float*)d_in[8];
  const float* Wg2 = (const float*)d_in[9];
  const float* bg2 = (const float*)d_in[10];
  const float* Wo = (const float*)d_in[11];
  const float* bo = (const float*)d_in[12];

  const int N = in_sizes[0] / 128;
  const int E = (int)(in_sizes[2] / 2);
  const int* rows = ei;
  const int* cols = ei + E;

  float* out1 = (float*)d_out;
  float* out2 = out1 + (long long)N * 64;

  // ws (4B units): dis[N] | deg[N] | off[N+16] | part[64] | s[N] | bvec[64] |
  //   csr int2[E] | S1 bf16[N*128] | S2 bf16[N*128] | S3 bf16[N*64] | P[53248]
  float* dis = (float*)d_ws;
  int* deg = (int*)(dis + N);
  int* off = deg + N;
  int* part = off + N + 16;
  float* s = (float*)(part + 64);
  float* bvec = s + N;
  int2* csr = (int2*)(bvec + 64);
  unsigned short* S1 = (unsigned short*)(csr + E);
  unsigned short* S2 = S1 + (long long)N * 128;
  unsigned short* S3 = S2 + (long long)N * 128;
  unsigned short* P = S3 + (long long)N * 64;
  unsigned short* pWis = P + 0;
  unsigned short* pWos0 = P + 16384;
  unsigned short* pWos1 = P + 24576;
  unsigned short* pWo0 = P + 32768;
  unsigned short* pWo1 = P + 40960;
  unsigned short* pW12 = P + 45056;

  const int NB = (N + 1023) / 1024;
  const int GB = N / 64;          // 625
  const int GGB = (N + 15) / 16;  // 2500: 1 node per 16-lane group

  const int cvtB = (N * 32 + 255) / 256;  // 5000
  const int zeroB = (N + 255) / 256;      // 157

  // --- prep (flat) + W12 (separate; direct packed write) ---
  prep_kernel<<<cvtB + zeroB + 22, 256, 0, stream>>>(
      x_self, S1, deg, Wis, Wos, Wo, P, cvtB, zeroB, N);
  w12_kernel<<<33, 256, 0, stream>>>(Wg1, Wg2, bg1, pW12, bvec);

  // --- CSR build + norms ---
  deg_kernel<<<(E + 255) / 256, 256, 0, stream>>>(cols, deg, E);
  scan1_kernel<<<NB, 1024, 0, stream>>>(deg, off, part, dis, N);
  scan3_kernel<<<NB, 1024, 0, stream>>>(off, part, N);
  fill_kernel<<<(E + 255) / 256, 256, 0, stream>>>(rows, cols, off, dis, csr, E);

  // --- self branch ---
  mfma_gemm_kernel<128, 0, 128, true, true, false>
      <<<GB, 256, 0, stream>>>(S1, nullptr, pWis, nullptr, bis, S2);
  mfma_gemm_kernel<128, 128, 64, false, false, false>
      <<<GB, 256, 0, stream>>>(S1, S2, pWos0, pWos1, bos, out1);

  // --- GCN branch: g2 = A·(A·(X·W12)) + s·(bg1·Wg2) + bg2 ---
  mfma_gemm_kernel<128, 0, 64, false, true, false>
      <<<GB, 256, 0, stream>>>(S1, nullptr, pW12, nullptr, nullptr, S2);
  gather64_kernel<false><<<GGB, 256, 0, stream>>>(
      S2, csr, off, dis, s, nullptr, nullptr, nullptr, S3, N);
  gather64_kernel<true><<<GGB, 256, 0, stream>>>(
      S3, csr, off, dis, nullptr, s, bvec, bg2, S1, N);
  mfma_gemm_kernel<128, 64, 64, false, false, true>
      <<<GB, 256, 0, stream>>>(x_nb, S1, pWo0, pWo1, bo, out2);
}

// Round 13
// 140.568 us; speedup vs baseline: 1.2369x; 1.0872x over previous
//
#include <hip/hip_runtime.h>
#include <hip/hip_fp16.h>

typedef short s8v __attribute__((ext_vector_type(8)));
typedef float f4v __attribute__((ext_vector_type(4)));
typedef unsigned short u16x8 __attribute__((ext_vector_type(8)));

__device__ __forceinline__ unsigned short f2bf(float f) {
  unsigned u = __float_as_uint(f);
  u = (u + 0x7fffu + ((u >> 16) & 1u)) >> 16;
  return (unsigned short)u;
}
__device__ __forceinline__ float bf2f(unsigned short s) {
  return __uint_as_float(((unsigned)s) << 16);
}

// ---------------------------------------------------------------------------
// Packed-weight region P (ushort offsets):
//   pWis  [0,16384)     pWos0 [16384,24576)  pWos1 [24576,32768)
//   pWo0  [32768,40960) pWo1  [40960,45056)  pW12  [45056,53248)
// Fragment order: P[((kc*(NC/16)+ct)*64+lane)*8+j] =
//                 bf16( W[kc*32+(lane>>4)*8+j][ct*16+(lane&15)] )
// ---------------------------------------------------------------------------
__device__ __forceinline__ void pack_one(const float* __restrict__ W,
                                         unsigned short* __restrict__ P,
                                         int NC, int t) {
  const int lane = t & 63;
  const int ct = (t >> 6) % (NC / 16);
  const int kc = (t >> 6) / (NC / 16);
  const int col = ct * 16 + (lane & 15);
  const int krow = kc * 32 + (lane >> 4) * 8;
  unsigned short tmp[8];
#pragma unroll
  for (int j = 0; j < 8; ++j) tmp[j] = f2bf(W[(krow + j) * NC + col]);
  uint4 o;
  o.x = (unsigned)tmp[0] | ((unsigned)tmp[1] << 16);
  o.y = (unsigned)tmp[2] | ((unsigned)tmp[3] << 16);
  o.z = (unsigned)tmp[4] | ((unsigned)tmp[5] << 16);
  o.w = (unsigned)tmp[6] | ((unsigned)tmp[7] << 16);
  reinterpret_cast<uint4*>(P)[t] = o;
}

// ---------------------------------------------------------------------------
// Flat prep:
//   blocks [0, cvtB)          : cvt x_self f32 -> bf16 S1
//   blocks [cvtB, cvtB+zeroB) : zero deg
//   + 22 pack blocks          : 8 Wis | 4 Wos0 | 4 Wos1 | 4 Wo0 | 2 Wo1
// ---------------------------------------------------------------------------
__global__ __launch_bounds__(256) void prep_kernel(
    const float* __restrict__ x, unsigned short* __restrict__ S1,
    int* __restrict__ deg, const float* __restrict__ Wis,
    const float* __restrict__ Wos, const float* __restrict__ Wo,
    unsigned short* __restrict__ P, int cvtB, int zeroB, int N) {
  const int blk = blockIdx.x;
  const int tid = threadIdx.x;
  if (blk < cvtB) {
    const int i = blk * 256 + tid;  // N*32 = 1.28M / 256 = 5000 exact
    const float4 v = reinterpret_cast<const float4*>(x)[i];
    ushort4 o;
    o.x = f2bf(v.x); o.y = f2bf(v.y); o.z = f2bf(v.z); o.w = f2bf(v.w);
    reinterpret_cast<ushort4*>(S1)[i] = o;
    return;
  }
  const int b1 = blk - cvtB;
  if (b1 < zeroB) {
    const int i = b1 * 256 + tid;
    if (i < N) deg[i] = 0;
    return;
  }
  const int b = b1 - zeroB;  // 0..21
  if (b < 8)        pack_one(Wis,            P + 0,     128, b * 256 + tid);
  else if (b < 12)  pack_one(Wos,            P + 16384, 64,  (b - 8) * 256 + tid);
  else if (b < 16)  pack_one(Wos + 128 * 64, P + 24576, 64,  (b - 12) * 256 + tid);
  else if (b < 20)  pack_one(Wo,             P + 32768, 64,  (b - 16) * 256 + tid);
  else              pack_one(Wo + 128 * 64,  P + 40960, 64,  (b - 20) * 256 + tid);
}

// ---------------------------------------------------------------------------
// deg count + W12 pack + bvec, one dispatch (independent block ranges).
// W12 element (i,j): kc=i>>5, lane=((i>>3)&3)*16+(j&15), jj=i&7, ct=j>>4
//   -> P12[((kc*4+ct)*64+lane)*8+jj]
// ---------------------------------------------------------------------------
__global__ __launch_bounds__(256) void deg_w12_kernel(
    const int* __restrict__ cols, int* __restrict__ deg, int E, int degB,
    const float* __restrict__ Wg1, const float* __restrict__ Wg2,
    const float* __restrict__ bg1, unsigned short* __restrict__ P12,
    float* __restrict__ bvec) {
  const int blk = blockIdx.x;
  if (blk < degB) {
    const int i = blk * 256 + threadIdx.x;
    if (i < E) atomicAdd(&deg[cols[i]], 1);
    return;
  }
  const int b = blk - degB;  // 0..32
  if (b < 32) {
    const int t = b * 256 + threadIdx.x;  // t = i*64 + j
    const int i = t >> 6, j = t & 63;
    float acc = 0.f;
    for (int k = 0; k < 128; ++k)
      acc = fmaf(Wg1[i * 128 + k], Wg2[k * 64 + j], acc);
    const int kc = i >> 5;
    const int lane = ((i >> 3) & 3) * 16 + (j & 15);
    const int jj = i & 7;
    const int ct = j >> 4;
    P12[((kc * 4 + ct) * 64 + lane) * 8 + jj] = f2bf(acc);
  } else if (threadIdx.x < 64) {
    const int j = threadIdx.x;
    float acc = 0.f;
    for (int k = 0; k < 128; ++k) acc = fmaf(bg1[k], Wg2[k * 64 + j], acc);
    bvec[j] = acc;
  }
}

// ---------------------------------------------------------------------------
// MFMA GEMM: C = A1[M x K1] @ B1 (+ A2[M x K2] @ B2) + bias, optional relu.
// ---------------------------------------------------------------------------
template <int K1, int K2, int NC, bool RELU, bool OUT_BF16, bool A1F32>
__global__ __launch_bounds__(256) void mfma_gemm_kernel(
    const void* __restrict__ A1v, const unsigned short* __restrict__ A2,
    const unsigned short* __restrict__ P1, const unsigned short* __restrict__ P2,
    const float* __restrict__ bias, void* __restrict__ Cout) {
  constexpr int NT = NC / 16;
  constexpr int KC1 = K1 / 32;
  constexpr int KC2 = (K2 > 0) ? (K2 / 32) : 1;
  __shared__ unsigned short Bs[(K1 + K2) * NC];

  {
    uint4* d = reinterpret_cast<uint4*>(Bs);
    constexpr int n1 = K1 * NC / 8;
    const uint4* s1 = reinterpret_cast<const uint4*>(P1);
    for (int i = threadIdx.x; i < n1; i += 256) d[i] = s1[i];
    if constexpr (K2 > 0) {
      constexpr int n2 = K2 * NC / 8;
      const uint4* s2 = reinterpret_cast<const uint4*>(P2);
      for (int i = threadIdx.x; i < n2; i += 256) d[n1 + i] = s2[i];
    }
  }

  const int wave = threadIdx.x >> 6;
  const int lane = threadIdx.x & 63;
  const int row0 = blockIdx.x * 64 + wave * 16;
  const int arow = row0 + (lane & 15);
  const int koff = (lane >> 4) * 8;

  s8v a1[KC1];
  if constexpr (A1F32) {
    const float* A1f = (const float*)A1v;
#pragma unroll
    for (int kc = 0; kc < KC1; ++kc) {
      const float4 f0 = *reinterpret_cast<const float4*>(
          A1f + (long long)arow * K1 + kc * 32 + koff);
      const float4 f1 = *reinterpret_cast<const float4*>(
          A1f + (long long)arow * K1 + kc * 32 + koff + 4);
      s8v r;
      r[0] = (short)f2bf(f0.x); r[1] = (short)f2bf(f0.y);
      r[2] = (short)f2bf(f0.z); r[3] = (short)f2bf(f0.w);
      r[4] = (short)f2bf(f1.x); r[5] = (short)f2bf(f1.y);
      r[6] = (short)f2bf(f1.z); r[7] = (short)f2bf(f1.w);
      a1[kc] = r;
    }
  } else {
    const unsigned short* A1b = (const unsigned short*)A1v;
#pragma unroll
    for (int kc = 0; kc < KC1; ++kc)
      a1[kc] = *reinterpret_cast<const s8v*>(A1b + (long long)arow * K1 +
                                             kc * 32 + koff);
  }
  s8v a2[KC2];
  if constexpr (K2 > 0) {
#pragma unroll
    for (int kc = 0; kc < K2 / 32; ++kc)
      a2[kc] = *reinterpret_cast<const s8v*>(A2 + (long long)arow * K2 +
                                             kc * 32 + koff);
  }

  __syncthreads();

  f4v acc[NT] = {};
#pragma unroll
  for (int kc = 0; kc < KC1; ++kc) {
#pragma unroll
    for (int ct = 0; ct < NT; ++ct) {
      const s8v b =
          *reinterpret_cast<const s8v*>(&Bs[((kc * NT + ct) * 64 + lane) * 8]);
      acc[ct] = __builtin_amdgcn_mfma_f32_16x16x32_bf16(a1[kc], b, acc[ct], 0, 0, 0);
    }
  }
  if constexpr (K2 > 0) {
#pragma unroll
    for (int kc = 0; kc < K2 / 32; ++kc) {
#pragma unroll
      for (int ct = 0; ct < NT; ++ct) {
        const s8v b = *reinterpret_cast<const s8v*>(
            &Bs[(((KC1 + kc) * NT + ct) * 64 + lane) * 8]);
        acc[ct] = __builtin_amdgcn_mfma_f32_16x16x32_bf16(a2[kc], b, acc[ct], 0, 0, 0);
      }
    }
  }

  const int crow0 = row0 + (lane >> 4) * 4;
  const int ccol = lane & 15;
#pragma unroll
  for (int ct = 0; ct < NT; ++ct) {
    const int col = ct * 16 + ccol;
    const float bv = bias ? bias[col] : 0.f;
#pragma unroll
    for (int r = 0; r < 4; ++r) {
      float v = acc[ct][r] + bv;
      if (RELU) v = fmaxf(v, 0.f);
      const long long idx = (long long)(crow0 + r) * NC + col;
      if (OUT_BF16)
        ((unsigned short*)Cout)[idx] = f2bf(v);
      else
        ((float*)Cout)[idx] = v;
    }
  }
}

// ---------------------------------------------------------------------------
// CSR build (scan + fill).  csr entry = 4 bytes: (fp16(w)<<16) | src.
// ---------------------------------------------------------------------------
__global__ __launch_bounds__(1024) void scan1_kernel(
    const int* __restrict__ deg, int* __restrict__ off, int* __restrict__ part,
    float* __restrict__ dis, int N) {
  __shared__ int s[1024];
  const int tid = threadIdx.x;
  const int i = blockIdx.x * 1024 + tid;
  const int v = (i < N) ? deg[i] : 0;
  if (i < N) dis[i] = rsqrtf((float)v + 1.0f);
  s[tid] = v;
  __syncthreads();
  for (int o = 1; o < 1024; o <<= 1) {
    const int t = (tid >= o) ? s[tid - o] : 0;
    __syncthreads();
    s[tid] += t;
    __syncthreads();
  }
  if (i < N) off[i] = s[tid] - v;
  if (tid == 1023) part[blockIdx.x] = s[1023];
}

__global__ __launch_bounds__(1024) void scan3_kernel(
    int* __restrict__ off, const int* __restrict__ part, int N) {
  __shared__ int pp;
  if (threadIdx.x < 64) {
    int v = (threadIdx.x < blockIdx.x) ? part[threadIdx.x] : 0;
#pragma unroll
    for (int o = 32; o > 0; o >>= 1) v += __shfl_down(v, o, 64);
    if (threadIdx.x == 0) pp = v;
  }
  __syncthreads();
  const int i = blockIdx.x * 1024 + threadIdx.x;
  if (i < N) off[i] += pp;
}

// csr[pos] = (fp16(dis[src]*dis[dst])<<16) | src.  Afterwards off[c]=END of c.
__global__ __launch_bounds__(256) void fill_kernel(
    const int* __restrict__ rows, const int* __restrict__ cols,
    int* __restrict__ off, const float* __restrict__ dis,
    unsigned* __restrict__ csr, int E) {
  const int i = blockIdx.x * 256 + threadIdx.x;
  if (i < E) {
    const int c = cols[i];
    const int r = rows[i];
    const int pos = atomicAdd(&off[c], 1);
    const unsigned wb = __half_as_ushort(__float2half(dis[r] * dis[c]));
    csr[pos] = (wb << 16) | (unsigned)r;
  }
}

// ---------------------------------------------------------------------------
// D=64 CSR gather, 8 nodes per wave (8-lane groups, ushort8=16B/lane).
// 8 independent edge chains per wave; group's 8 lanes x 16B = 128B row.
// Pass A: out[n]=A·h (bf16), s_out[n]=Σw+dn².  Pass B: + s_in*bvec + bias.
// ---------------------------------------------------------------------------
template <bool PASS_B>
__global__ __launch_bounds__(256) void gather64_kernel(
    const unsigned short* __restrict__ h, const unsigned* __restrict__ csr,
    const int* __restrict__ off, const float* __restrict__ dis,
    float* __restrict__ s_out, const float* __restrict__ s_in,
    const float* __restrict__ bvec, const float* __restrict__ bias,
    unsigned short* __restrict__ out, int N) {
  const int wid = (blockIdx.x * 256 + threadIdx.x) >> 6;
  const int lane = threadIdx.x & 63;
  const int grp = lane >> 3;   // node slot 0..7
  const int sl = lane & 7;     // feature octet (8 features)
  const int stride = gridDim.x * 32;  // waves*8 nodes

  float bb[8], bv[8];
  if constexpr (PASS_B) {
    const float4 b0 = *reinterpret_cast<const float4*>(bias + sl * 8);
    const float4 b1 = *reinterpret_cast<const float4*>(bias + sl * 8 + 4);
    bb[0] = b0.x; bb[1] = b0.y; bb[2] = b0.z; bb[3] = b0.w;
    bb[4] = b1.x; bb[5] = b1.y; bb[6] = b1.z; bb[7] = b1.w;
    const float4 v0 = *reinterpret_cast<const float4*>(bvec + sl * 8);
    const float4 v1 = *reinterpret_cast<const float4*>(bvec + sl * 8 + 4);
    bv[0] = v0.x; bv[1] = v0.y; bv[2] = v0.z; bv[3] = v0.w;
    bv[4] = v1.x; bv[5] = v1.y; bv[6] = v1.z; bv[7] = v1.w;
  }

  for (int n = wid * 8 + grp; n < N; n += stride) {
    const float dn = dis[n];
    const float dn2 = dn * dn;
    float a[8];
    {
      const u16x8 hv =
          *reinterpret_cast<const u16x8*>(h + (long long)n * 64 + sl * 8);
#pragma unroll
      for (int q = 0; q < 8; ++q) a[q] = bf2f(hv[q]) * dn2;
    }
    float sw = dn2;
    const int start = (n == 0) ? 0 : off[n - 1];
    const int end = off[n];
    int j = start;
    for (; j + 3 < end; j += 4) {
      const unsigned e0 = csr[j], e1 = csr[j + 1];
      const unsigned e2 = csr[j + 2], e3 = csr[j + 3];
      const u16x8 u0 = *reinterpret_cast<const u16x8*>(
          h + (long long)(e0 & 0xffffu) * 64 + sl * 8);
      const u16x8 u1 = *reinterpret_cast<const u16x8*>(
          h + (long long)(e1 & 0xffffu) * 64 + sl * 8);
      const u16x8 u2 = *reinterpret_cast<const u16x8*>(
          h + (long long)(e2 & 0xffffu) * 64 + sl * 8);
      const u16x8 u3 = *reinterpret_cast<const u16x8*>(
          h + (long long)(e3 & 0xffffu) * 64 + sl * 8);
      const float w0 = __half2float(__ushort_as_half((unsigned short)(e0 >> 16)));
      const float w1 = __half2float(__ushort_as_half((unsigned short)(e1 >> 16)));
      const float w2 = __half2float(__ushort_as_half((unsigned short)(e2 >> 16)));
      const float w3 = __half2float(__ushort_as_half((unsigned short)(e3 >> 16)));
#pragma unroll
      for (int q = 0; q < 8; ++q) {
        a[q] = fmaf(bf2f(u0[q]), w0, a[q]);
        a[q] = fmaf(bf2f(u1[q]), w1, a[q]);
        a[q] = fmaf(bf2f(u2[q]), w2, a[q]);
        a[q] = fmaf(bf2f(u3[q]), w3, a[q]);
      }
      if constexpr (!PASS_B) sw += (w0 + w1) + (w2 + w3);
    }
    for (; j < end; ++j) {
      const unsigned e = csr[j];
      const u16x8 u = *reinterpret_cast<const u16x8*>(
          h + (long long)(e & 0xffffu) * 64 + sl * 8);
      const float w = __half2float(__ushort_as_half((unsigned short)(e >> 16)));
#pragma unroll
      for (int q = 0; q < 8; ++q) a[q] = fmaf(bf2f(u[q]), w, a[q]);
      if constexpr (!PASS_B) sw += w;
    }
    u16x8 o;
    if constexpr (!PASS_B) {
      if (sl == 0) s_out[n] = sw;
#pragma unroll
      for (int q = 0; q < 8; ++q) o[q] = f2bf(a[q]);
    } else {
      const float si = s_in[n];
#pragma unroll
      for (int q = 0; q < 8; ++q) o[q] = f2bf(fmaf(si, bv[q], a[q] + bb[q]));
    }
    *reinterpret_cast<u16x8*>(out + (long long)n * 64 + sl * 8) = o;
  }
}

extern "C" void kernel_launch(void* const* d_in, const int* in_sizes, int n_in,
                              void* d_out, int out_size, void* d_ws,
                              size_t ws_size, hipStream_t stream) {
  const float* x_self = (const float*)d_in[0];
  const float* x_nb = (const float*)d_in[1];
  const int* ei = (const int*)d_in[2];
  const float* Wis = (const float*)d_in[3];
  const float* bis = (const float*)d_in[4];
  const float* Wos = (const float*)d_in[5];
  const float* bos = (const float*)d_in[6];
  const float* Wg1 = (const float*)d_in[7];
  const float* bg1 = (const float*)d_in[8];
  const float* Wg2 = (const float*)d_in[9];
  const float* bg2 = (const float*)d_in[10];
  const float* Wo = (const float*)d_in[11];
  const float* bo = (const float*)d_in[12];

  const int N = in_sizes[0] / 128;
  const int E = (int)(in_sizes[2] / 2);
  const int* rows = ei;
  const int* cols = ei + E;

  float* out1 = (float*)d_out;
  float* out2 = out1 + (long long)N * 64;

  // ws (4B units): dis[N] | deg[N] | off[N+16] | part[64] | s[N] | bvec[64] |
  //   csr uint[E] | S1 bf16[N*128] | S2 bf16[N*128] | S3 bf16[N*64] | P[53248]
  float* dis = (float*)d_ws;
  int* deg = (int*)(dis + N);
  int* off = deg + N;
  int* part = off + N + 16;
  float* s = (float*)(part + 64);
  float* bvec = s + N;
  unsigned* csr = (unsigned*)(bvec + 64);
  unsigned short* S1 = (unsigned short*)(csr + E);
  unsigned short* S2 = S1 + (long long)N * 128;
  unsigned short* S3 = S2 + (long long)N * 128;
  unsigned short* P = S3 + (long long)N * 64;
  unsigned short* pWis = P + 0;
  unsigned short* pWos0 = P + 16384;
  unsigned short* pWos1 = P + 24576;
  unsigned short* pWo0 = P + 32768;
  unsigned short* pWo1 = P + 40960;
  unsigned short* pW12 = P + 45056;

  const int NB = (N + 1023) / 1024;
  const int GB = N / 64;          // 625
  const int GGB = (N + 31) / 32;  // 1250: 1 node per 8-lane group

  const int cvtB = (N * 32 + 255) / 256;  // 5000
  const int zeroB = (N + 255) / 256;      // 157
  const int degB = (E + 255) / 256;       // 2500

  // --- prep (flat) ---
  prep_kernel<<<cvtB + zeroB + 22, 256, 0, stream>>>(
      x_self, S1, deg, Wis, Wos, Wo, P, cvtB, zeroB, N);
  // --- deg count + W12 pack + bvec (one dispatch) ---
  deg_w12_kernel<<<degB + 33, 256, 0, stream>>>(cols, deg, E, degB, Wg1, Wg2,
                                                bg1, pW12, bvec);
  // --- scan + fill ---
  scan1_kernel<<<NB, 1024, 0, stream>>>(deg, off, part, dis, N);
  scan3_kernel<<<NB, 1024, 0, stream>>>(off, part, N);
  fill_kernel<<<degB, 256, 0, stream>>>(rows, cols, off, dis, csr, E);

  // --- self branch ---
  mfma_gemm_kernel<128, 0, 128, true, true, false>
      <<<GB, 256, 0, stream>>>(S1, nullptr, pWis, nullptr, bis, S2);
  mfma_gemm_kernel<128, 128, 64, false, false, false>
      <<<GB, 256, 0, stream>>>(S1, S2, pWos0, pWos1, bos, out1);

  // --- GCN branch: g2 = A·(A·(X·W12)) + s·(bg1·Wg2) + bg2 ---
  mfma_gemm_kernel<128, 0, 64, false, true, false>
      <<<GB, 256, 0, stream>>>(S1, nullptr, pW12, nullptr, nullptr, S2);
  gather64_kernel<false><<<GGB, 256, 0, stream>>>(
      S2, csr, off, dis, s, nullptr, nullptr, nullptr, S3, N);
  gather64_kernel<true><<<GGB, 256, 0, stream>>>(
      S3, csr, off, dis, nullptr, s, bvec, bg2, S1, N);
  mfma_gemm_kernel<128, 64, 64, false, false, true>
      <<<GB, 256, 0, stream>>>(x_nb, S1, pWo0, pWo1, bo, out2);
}

// Round 14
// 132.657 us; speedup vs baseline: 1.3107x; 1.0596x over previous
//
#include <hip/hip_runtime.h>
#include <hip/hip_fp16.h>

typedef short s8v __attribute__((ext_vector_type(8)));
typedef float f4v __attribute__((ext_vector_type(4)));
typedef unsigned short u16x8 __attribute__((ext_vector_type(8)));

__device__ __forceinline__ unsigned short f2bf(float f) {
  unsigned u = __float_as_uint(f);
  u = (u + 0x7fffu + ((u >> 16) & 1u)) >> 16;
  return (unsigned short)u;
}
__device__ __forceinline__ float bf2f(unsigned short s) {
  return __uint_as_float(((unsigned)s) << 16);
}

// ---------------------------------------------------------------------------
// Packed-weight region P (ushort offsets):
//   pWis  [0,16384)     pWos0 [16384,24576)  pWos1 [24576,32768)
//   pWo0  [32768,40960) pWo1  [40960,45056)  pW12  [45056,53248)
// Fragment order: P[((kc*(NC/16)+ct)*64+lane)*8+j] =
//                 bf16( W[kc*32+(lane>>4)*8+j][ct*16+(lane&15)] )
// ---------------------------------------------------------------------------
__device__ __forceinline__ void pack_one(const float* __restrict__ W,
                                         unsigned short* __restrict__ P,
                                         int NC, int t) {
  const int lane = t & 63;
  const int ct = (t >> 6) % (NC / 16);
  const int kc = (t >> 6) / (NC / 16);
  const int col = ct * 16 + (lane & 15);
  const int krow = kc * 32 + (lane >> 4) * 8;
  unsigned short tmp[8];
#pragma unroll
  for (int j = 0; j < 8; ++j) tmp[j] = f2bf(W[(krow + j) * NC + col]);
  uint4 o;
  o.x = (unsigned)tmp[0] | ((unsigned)tmp[1] << 16);
  o.y = (unsigned)tmp[2] | ((unsigned)tmp[3] << 16);
  o.z = (unsigned)tmp[4] | ((unsigned)tmp[5] << 16);
  o.w = (unsigned)tmp[6] | ((unsigned)tmp[7] << 16);
  reinterpret_cast<uint4*>(P)[t] = o;
}

// ---------------------------------------------------------------------------
// Flat prep: cvt x_self -> bf16 | zero deg | 22 weight-pack blocks
// ---------------------------------------------------------------------------
__global__ __launch_bounds__(256) void prep_kernel(
    const float* __restrict__ x, unsigned short* __restrict__ S1,
    int* __restrict__ deg, const float* __restrict__ Wis,
    const float* __restrict__ Wos, const float* __restrict__ Wo,
    unsigned short* __restrict__ P, int cvtB, int zeroB, int N) {
  const int blk = blockIdx.x;
  const int tid = threadIdx.x;
  if (blk < cvtB) {
    const int i = blk * 256 + tid;
    const float4 v = reinterpret_cast<const float4*>(x)[i];
    ushort4 o;
    o.x = f2bf(v.x); o.y = f2bf(v.y); o.z = f2bf(v.z); o.w = f2bf(v.w);
    reinterpret_cast<ushort4*>(S1)[i] = o;
    return;
  }
  const int b1 = blk - cvtB;
  if (b1 < zeroB) {
    const int i = b1 * 256 + tid;
    if (i < N) deg[i] = 0;
    return;
  }
  const int b = b1 - zeroB;  // 0..21
  if (b < 8)        pack_one(Wis,            P + 0,     128, b * 256 + tid);
  else if (b < 12)  pack_one(Wos,            P + 16384, 64,  (b - 8) * 256 + tid);
  else if (b < 16)  pack_one(Wos + 128 * 64, P + 24576, 64,  (b - 12) * 256 + tid);
  else if (b < 20)  pack_one(Wo,             P + 32768, 64,  (b - 16) * 256 + tid);
  else              pack_one(Wo + 128 * 64,  P + 40960, 64,  (b - 20) * 256 + tid);
}

// ---------------------------------------------------------------------------
// deg count + W12 pack + bvec, one dispatch (independent block ranges).
// ---------------------------------------------------------------------------
__global__ __launch_bounds__(256) void deg_w12_kernel(
    const int* __restrict__ cols, int* __restrict__ deg, int E, int degB,
    const float* __restrict__ Wg1, const float* __restrict__ Wg2,
    const float* __restrict__ bg1, unsigned short* __restrict__ P12,
    float* __restrict__ bvec) {
  const int blk = blockIdx.x;
  if (blk < degB) {
    const int i = blk * 256 + threadIdx.x;
    if (i < E) atomicAdd(&deg[cols[i]], 1);
    return;
  }
  const int b = blk - degB;  // 0..32
  if (b < 32) {
    const int t = b * 256 + threadIdx.x;  // t = i*64 + j
    const int i = t >> 6, j = t & 63;
    float acc = 0.f;
    for (int k = 0; k < 128; ++k)
      acc = fmaf(Wg1[i * 128 + k], Wg2[k * 64 + j], acc);
    const int kc = i >> 5;
    const int lane = ((i >> 3) & 3) * 16 + (j & 15);
    const int jj = i & 7;
    const int ct = j >> 4;
    P12[((kc * 4 + ct) * 64 + lane) * 8 + jj] = f2bf(acc);
  } else if (threadIdx.x < 64) {
    const int j = threadIdx.x;
    float acc = 0.f;
    for (int k = 0; k < 128; ++k) acc = fmaf(bg1[k], Wg2[k * 64 + j], acc);
    bvec[j] = acc;
  }
}

// ---------------------------------------------------------------------------
// Shared GEMM body (block-range callable). LDS passed in; identical math to
// the proven mfma_gemm_kernel. ACCUM: += existing f32 C.
// ---------------------------------------------------------------------------
template <int K1, int K2, int NC, bool RELU, bool OUT_BF16, bool A1F32, bool ACCUM>
__device__ __forceinline__ void gemm_body(
    unsigned short* __restrict__ Bs, const void* __restrict__ A1v,
    const unsigned short* __restrict__ A2, const unsigned short* __restrict__ P1,
    const unsigned short* __restrict__ P2, const float* __restrict__ bias,
    void* __restrict__ Cout, int blk) {
  constexpr int NT = NC / 16;
  constexpr int KC1 = K1 / 32;
  constexpr int KC2 = (K2 > 0) ? (K2 / 32) : 1;
  const int tid = threadIdx.x;
  {
    uint4* d = reinterpret_cast<uint4*>(Bs);
    constexpr int n1 = K1 * NC / 8;
    const uint4* s1 = reinterpret_cast<const uint4*>(P1);
    for (int i = tid; i < n1; i += 256) d[i] = s1[i];
    if constexpr (K2 > 0) {
      constexpr int n2 = K2 * NC / 8;
      const uint4* s2 = reinterpret_cast<const uint4*>(P2);
      for (int i = tid; i < n2; i += 256) d[n1 + i] = s2[i];
    }
  }

  const int wave = tid >> 6;
  const int lane = tid & 63;
  const int row0 = blk * 64 + wave * 16;
  const int arow = row0 + (lane & 15);
  const int koff = (lane >> 4) * 8;

  s8v a1[KC1];
  if constexpr (A1F32) {
    const float* A1f = (const float*)A1v;
#pragma unroll
    for (int kc = 0; kc < KC1; ++kc) {
      const float4 f0 = *reinterpret_cast<const float4*>(
          A1f + (long long)arow * K1 + kc * 32 + koff);
      const float4 f1 = *reinterpret_cast<const float4*>(
          A1f + (long long)arow * K1 + kc * 32 + koff + 4);
      s8v r;
      r[0] = (short)f2bf(f0.x); r[1] = (short)f2bf(f0.y);
      r[2] = (short)f2bf(f0.z); r[3] = (short)f2bf(f0.w);
      r[4] = (short)f2bf(f1.x); r[5] = (short)f2bf(f1.y);
      r[6] = (short)f2bf(f1.z); r[7] = (short)f2bf(f1.w);
      a1[kc] = r;
    }
  } else {
    const unsigned short* A1b = (const unsigned short*)A1v;
#pragma unroll
    for (int kc = 0; kc < KC1; ++kc)
      a1[kc] = *reinterpret_cast<const s8v*>(A1b + (long long)arow * K1 +
                                             kc * 32 + koff);
  }
  s8v a2[KC2];
  if constexpr (K2 > 0) {
#pragma unroll
    for (int kc = 0; kc < K2 / 32; ++kc)
      a2[kc] = *reinterpret_cast<const s8v*>(A2 + (long long)arow * K2 +
                                             kc * 32 + koff);
  }

  __syncthreads();

  f4v acc[NT] = {};
#pragma unroll
  for (int kc = 0; kc < KC1; ++kc) {
#pragma unroll
    for (int ct = 0; ct < NT; ++ct) {
      const s8v b =
          *reinterpret_cast<const s8v*>(&Bs[((kc * NT + ct) * 64 + lane) * 8]);
      acc[ct] = __builtin_amdgcn_mfma_f32_16x16x32_bf16(a1[kc], b, acc[ct], 0, 0, 0);
    }
  }
  if constexpr (K2 > 0) {
#pragma unroll
    for (int kc = 0; kc < K2 / 32; ++kc) {
#pragma unroll
      for (int ct = 0; ct < NT; ++ct) {
        const s8v b = *reinterpret_cast<const s8v*>(
            &Bs[(((KC1 + kc) * NT + ct) * 64 + lane) * 8]);
        acc[ct] = __builtin_amdgcn_mfma_f32_16x16x32_bf16(a2[kc], b, acc[ct], 0, 0, 0);
      }
    }
  }

  const int crow0 = row0 + (lane >> 4) * 4;
  const int ccol = lane & 15;
#pragma unroll
  for (int ct = 0; ct < NT; ++ct) {
    const int col = ct * 16 + ccol;
    const float bv = bias ? bias[col] : 0.f;
#pragma unroll
    for (int r = 0; r < 4; ++r) {
      const long long idx = (long long)(crow0 + r) * NC + col;
      float v = acc[ct][r] + bv;
      if (ACCUM) v += ((float*)Cout)[idx];
      if (RELU) v = fmaxf(v, 0.f);
      if (OUT_BF16)
        ((unsigned short*)Cout)[idx] = f2bf(v);
      else
        ((float*)Cout)[idx] = v;
    }
  }
}

// ---------------------------------------------------------------------------
// Shared gather body: 8 nodes/wave (8-lane groups, ushort8), 4-unroll.
// Pass A: out[n]=A·h, s_out[n]=Σw+dn².  Pass B: + s_in*bvec + bias.
// ---------------------------------------------------------------------------
template <bool PASS_B>
__device__ __forceinline__ void gather_body(
    const unsigned short* __restrict__ h, const unsigned* __restrict__ csr,
    const int* __restrict__ off, const float* __restrict__ dis,
    float* __restrict__ s_out, const float* __restrict__ s_in,
    const float* __restrict__ bvec, const float* __restrict__ bias,
    unsigned short* __restrict__ out, int N, int gb, int nblk) {
  const int wid = (gb * 256 + (int)threadIdx.x) >> 6;
  const int lane = threadIdx.x & 63;
  const int grp = lane >> 3;
  const int sl = lane & 7;
  const int stride = nblk * 32;

  float bb[8], bv[8];
  if constexpr (PASS_B) {
    const float4 b0 = *reinterpret_cast<const float4*>(bias + sl * 8);
    const float4 b1 = *reinterpret_cast<const float4*>(bias + sl * 8 + 4);
    bb[0] = b0.x; bb[1] = b0.y; bb[2] = b0.z; bb[3] = b0.w;
    bb[4] = b1.x; bb[5] = b1.y; bb[6] = b1.z; bb[7] = b1.w;
    const float4 v0 = *reinterpret_cast<const float4*>(bvec + sl * 8);
    const float4 v1 = *reinterpret_cast<const float4*>(bvec + sl * 8 + 4);
    bv[0] = v0.x; bv[1] = v0.y; bv[2] = v0.z; bv[3] = v0.w;
    bv[4] = v1.x; bv[5] = v1.y; bv[6] = v1.z; bv[7] = v1.w;
  }

  for (int n = wid * 8 + grp; n < N; n += stride) {
    const float dn = dis[n];
    const float dn2 = dn * dn;
    float a[8];
    {
      const u16x8 hv =
          *reinterpret_cast<const u16x8*>(h + (long long)n * 64 + sl * 8);
#pragma unroll
      for (int q = 0; q < 8; ++q) a[q] = bf2f(hv[q]) * dn2;
    }
    float sw = dn2;
    const int start = (n == 0) ? 0 : off[n - 1];
    const int end = off[n];
    int j = start;
    for (; j + 3 < end; j += 4) {
      const unsigned e0 = csr[j], e1 = csr[j + 1];
      const unsigned e2 = csr[j + 2], e3 = csr[j + 3];
      const u16x8 u0 = *reinterpret_cast<const u16x8*>(
          h + (long long)(e0 & 0xffffu) * 64 + sl * 8);
      const u16x8 u1 = *reinterpret_cast<const u16x8*>(
          h + (long long)(e1 & 0xffffu) * 64 + sl * 8);
      const u16x8 u2 = *reinterpret_cast<const u16x8*>(
          h + (long long)(e2 & 0xffffu) * 64 + sl * 8);
      const u16x8 u3 = *reinterpret_cast<const u16x8*>(
          h + (long long)(e3 & 0xffffu) * 64 + sl * 8);
      const float w0 = __half2float(__ushort_as_half((unsigned short)(e0 >> 16)));
      const float w1 = __half2float(__ushort_as_half((unsigned short)(e1 >> 16)));
      const float w2 = __half2float(__ushort_as_half((unsigned short)(e2 >> 16)));
      const float w3 = __half2float(__ushort_as_half((unsigned short)(e3 >> 16)));
#pragma unroll
      for (int q = 0; q < 8; ++q) {
        a[q] = fmaf(bf2f(u0[q]), w0, a[q]);
        a[q] = fmaf(bf2f(u1[q]), w1, a[q]);
        a[q] = fmaf(bf2f(u2[q]), w2, a[q]);
        a[q] = fmaf(bf2f(u3[q]), w3, a[q]);
      }
      if constexpr (!PASS_B) sw += (w0 + w1) + (w2 + w3);
    }
    for (; j < end; ++j) {
      const unsigned e = csr[j];
      const u16x8 u = *reinterpret_cast<const u16x8*>(
          h + (long long)(e & 0xffffu) * 64 + sl * 8);
      const float w = __half2float(__ushort_as_half((unsigned short)(e >> 16)));
#pragma unroll
      for (int q = 0; q < 8; ++q) a[q] = fmaf(bf2f(u[q]), w, a[q]);
      if constexpr (!PASS_B) sw += w;
    }
    u16x8 o;
    if constexpr (!PASS_B) {
      if (sl == 0) s_out[n] = sw;
#pragma unroll
      for (int q = 0; q < 8; ++q) o[q] = f2bf(a[q]);
    } else {
      const float si = s_in[n];
#pragma unroll
      for (int q = 0; q < 8; ++q) o[q] = f2bf(fmaf(si, bv[q], a[q] + bb[q]));
    }
    *reinterpret_cast<u16x8*>(out + (long long)n * 64 + sl * 8) = o;
  }
}

// ---------------------------------------------------------------------------
// CSR scan
// ---------------------------------------------------------------------------
__global__ __launch_bounds__(1024) void scan1_kernel(
    const int* __restrict__ deg, int* __restrict__ off, int* __restrict__ part,
    float* __restrict__ dis, int N) {
  __shared__ int s[1024];
  const int tid = threadIdx.x;
  const int i = blockIdx.x * 1024 + tid;
  const int v = (i < N) ? deg[i] : 0;
  if (i < N) dis[i] = rsqrtf((float)v + 1.0f);
  s[tid] = v;
  __syncthreads();
  for (int o = 1; o < 1024; o <<= 1) {
    const int t = (tid >= o) ? s[tid - o] : 0;
    __syncthreads();
    s[tid] += t;
    __syncthreads();
  }
  if (i < N) off[i] = s[tid] - v;
  if (tid == 1023) part[blockIdx.x] = s[1023];
}

__global__ __launch_bounds__(1024) void scan3_kernel(
    int* __restrict__ off, const int* __restrict__ part, int N) {
  __shared__ int pp;
  if (threadIdx.x < 64) {
    int v = (threadIdx.x < blockIdx.x) ? part[threadIdx.x] : 0;
#pragma unroll
    for (int o = 32; o > 0; o >>= 1) v += __shfl_down(v, o, 64);
    if (threadIdx.x == 0) pp = v;
  }
  __syncthreads();
  const int i = blockIdx.x * 1024 + threadIdx.x;
  if (i < N) off[i] += pp;
}

// ---------------------------------------------------------------------------
// MEGA: GEMM1(h) | GEMM3(x@W12) | out2a(x_nb@Wo0+bo) | fill(csr)
// Ranges: [0,GB) | [GB,2GB) | [2GB,3GB) | [3GB, 3GB+degB)
// ---------------------------------------------------------------------------
__global__ __launch_bounds__(256) void mega_kernel(
    const unsigned short* __restrict__ S1, const float* __restrict__ x_nb,
    const unsigned short* __restrict__ P, const float* __restrict__ bis,
    const float* __restrict__ bo, unsigned short* __restrict__ S2h,
    unsigned short* __restrict__ S4, float* __restrict__ out2,
    const int* __restrict__ rows, const int* __restrict__ cols,
    int* __restrict__ off, const float* __restrict__ dis,
    unsigned* __restrict__ csr, int E, int GB) {
  __shared__ unsigned short Bs[16384];  // 32 KB
  const int b = blockIdx.x;
  if (b < GB) {
    gemm_body<128, 0, 128, true, true, false, false>(
        Bs, S1, nullptr, P + 0, nullptr, bis, S2h, b);
  } else if (b < 2 * GB) {
    gemm_body<128, 0, 64, false, true, false, false>(
        Bs, S1, nullptr, P + 45056, nullptr, nullptr, S4, b - GB);
  } else if (b < 3 * GB) {
    gemm_body<128, 0, 64, false, false, true, false>(
        Bs, x_nb, nullptr, P + 32768, nullptr, bo, out2, b - 2 * GB);
  } else {
    const int i = (b - 3 * GB) * 256 + (int)threadIdx.x;
    if (i < E) {
      const int c = cols[i];
      const int r = rows[i];
      const int pos = atomicAdd(&off[c], 1);
      const unsigned wb = __half_as_ushort(__float2half(dis[r] * dis[c]));
      csr[pos] = (wb << 16) | (unsigned)r;
    }
  }
}

// ---------------------------------------------------------------------------
// G2GA: GEMM2(out1) | gatherA.  Ranges: [0,GB) | [GB, GB+GGB)
// ---------------------------------------------------------------------------
__global__ __launch_bounds__(256) void g2ga_kernel(
    const unsigned short* __restrict__ S1, const unsigned short* __restrict__ S2h,
    const unsigned short* __restrict__ P, const float* __restrict__ bos,
    float* __restrict__ out1, const unsigned short* __restrict__ S4,
    const unsigned* __restrict__ csr, const int* __restrict__ off,
    const float* __restrict__ dis, float* __restrict__ s_out,
    unsigned short* __restrict__ S3, int N, int GB, int GGB) {
  __shared__ unsigned short Bs[16384];  // 32 KB
  const int b = blockIdx.x;
  if (b < GB) {
    gemm_body<128, 128, 64, false, false, false, false>(
        Bs, S1, S2h, P + 16384, P + 24576, bos, out1, b);
  } else {
    gather_body<false>(S4, csr, off, dis, s_out, nullptr, nullptr, nullptr, S3,
                       N, b - GB, GGB);
  }
}

__global__ __launch_bounds__(256) void gatherB_kernel(
    const unsigned short* __restrict__ S3, const unsigned* __restrict__ csr,
    const int* __restrict__ off, const float* __restrict__ dis,
    const float* __restrict__ s_in, const float* __restrict__ bvec,
    const float* __restrict__ bias, unsigned short* __restrict__ G2, int N) {
  gather_body<true>(S3, csr, off, dis, nullptr, s_in, bvec, bias, G2, N,
                    blockIdx.x, gridDim.x);
}

// out2 += g2 @ Wo1   (K=64 accumulate GEMM)
__global__ __launch_bounds__(256) void g4b_kernel(
    const unsigned short* __restrict__ G2, const unsigned short* __restrict__ P,
    float* __restrict__ out2) {
  __shared__ unsigned short Bs[4096];  // 8 KB
  gemm_body<64, 0, 64, false, false, false, true>(
      Bs, G2, nullptr, P + 40960, nullptr, nullptr, out2, blockIdx.x);
}

extern "C" void kernel_launch(void* const* d_in, const int* in_sizes, int n_in,
                              void* d_out, int out_size, void* d_ws,
                              size_t ws_size, hipStream_t stream) {
  const float* x_self = (const float*)d_in[0];
  const float* x_nb = (const float*)d_in[1];
  const int* ei = (const int*)d_in[2];
  const float* Wis = (const float*)d_in[3];
  const float* bis = (const float*)d_in[4];
  const float* Wos = (const float*)d_in[5];
  const float* bos = (const float*)d_in[6];
  const float* Wg1 = (const float*)d_in[7];
  const float* bg1 = (const float*)d_in[8];
  const float* Wg2 = (const float*)d_in[9];
  const float* bg2 = (const float*)d_in[10];
  const float* Wo = (const float*)d_in[11];
  const float* bo = (const float*)d_in[12];

  const int N = in_sizes[0] / 128;
  const int E = (int)(in_sizes[2] / 2);
  const int* rows = ei;
  const int* cols = ei + E;

  float* out1 = (float*)d_out;
  float* out2 = out1 + (long long)N * 64;

  // ws (4B units): dis[N] | deg[N] | off[N+16] | part[64] | s[N] | bvec[64] |
  //   csr uint[E] | S1 bf16[N*128] | S2h bf16[N*128] | S3 bf16[N*64] |
  //   S4 bf16[N*64] | P[53248]
  float* dis = (float*)d_ws;
  int* deg = (int*)(dis + N);
  int* off = deg + N;
  int* part = off + N + 16;
  float* s = (float*)(part + 64);
  float* bvec = s + N;
  unsigned* csr = (unsigned*)(bvec + 64);
  unsigned short* S1 = (unsigned short*)(csr + E);
  unsigned short* S2h = S1 + (long long)N * 128;
  unsigned short* S3 = S2h + (long long)N * 128;
  unsigned short* S4 = S3 + (long long)N * 64;
  unsigned short* P = S4 + (long long)N * 64;
  unsigned short* pW12 = P + 45056;

  const int NB = (N + 1023) / 1024;  // 40
  const int GB = N / 64;             // 625
  const int GGB = (N + 31) / 32;     // 1250: 1 node per 8-lane group

  const int cvtB = (N * 32 + 255) / 256;  // 5000
  const int zeroB = (N + 255) / 256;      // 157
  const int degB = (E + 255) / 256;       // 2500

  // 1. prep: cvt | zero deg | pack Wis/Wos/Wo
  prep_kernel<<<cvtB + zeroB + 22, 256, 0, stream>>>(
      x_self, S1, deg, Wis, Wos, Wo, P, cvtB, zeroB, N);
  // 2. deg count | W12 pack | bvec
  deg_w12_kernel<<<degB + 33, 256, 0, stream>>>(cols, deg, E, degB, Wg1, Wg2,
                                                bg1, pW12, bvec);
  // 3-4. scan
  scan1_kernel<<<NB, 1024, 0, stream>>>(deg, off, part, dis, N);
  scan3_kernel<<<NB, 1024, 0, stream>>>(off, part, N);
  // 5. MEGA: GEMM1 | GEMM3 | out2a | fill
  mega_kernel<<<3 * GB + degB, 256, 0, stream>>>(
      S1, x_nb, P, bis, bo, S2h, S4, out2, rows, cols, off, dis, csr, E, GB);
  // 6. GEMM2 | gatherA
  g2ga_kernel<<<GB + GGB, 256, 0, stream>>>(S1, S2h, P, bos, out1, S4, csr,
                                            off, dis, s, S3, N, GB, GGB);
  // 7. gatherB
  gatherB_kernel<<<GGB, 256, 0, stream>>>(S3, csr, off, dis, s, bvec, bg2, S1, N);
  // 8. out2 += g2 @ Wo1
  g4b_kernel<<<GB, 256, 0, stream>>>(S1, P, out2);
}

// Round 15
// 130.273 us; speedup vs baseline: 1.3346x; 1.0183x over previous
//
#include <hip/hip_runtime.h>
#include <hip/hip_fp16.h>

typedef short s8v __attribute__((ext_vector_type(8)));
typedef float f4v __attribute__((ext_vector_type(4)));
typedef unsigned short u16x8 __attribute__((ext_vector_type(8)));

__device__ __forceinline__ unsigned short f2bf(float f) {
  unsigned u = __float_as_uint(f);
  u = (u + 0x7fffu + ((u >> 16) & 1u)) >> 16;
  return (unsigned short)u;
}
__device__ __forceinline__ float bf2f(unsigned short s) {
  return __uint_as_float(((unsigned)s) << 16);
}

// ---------------------------------------------------------------------------
// Packed-weight region P (ushort offsets):
//   pWisA [0,8192)      Wis cols 0-63    pWisB [8192,16384)  Wis cols 64-127
//   pWos0 [16384,24576) pWos1 [24576,32768)
//   pWo0  [32768,40960) pWo1  [40960,45056)  pW12 [45056,53248)
// Fragment order (NCf=64 unless noted): P[((kc*(NCf/16)+ct)*64+lane)*8+j] =
//   bf16( W[(kc*32+(lane>>4)*8+j)*stride + ct*16+(lane&15)] )
// ---------------------------------------------------------------------------
__device__ __forceinline__ void pack_one(const float* __restrict__ W,
                                         unsigned short* __restrict__ P,
                                         int NCf, int stride, int t) {
  const int lane = t & 63;
  const int ct = (t >> 6) % (NCf / 16);
  const int kc = (t >> 6) / (NCf / 16);
  const int col = ct * 16 + (lane & 15);
  const int krow = kc * 32 + (lane >> 4) * 8;
  unsigned short tmp[8];
#pragma unroll
  for (int j = 0; j < 8; ++j) tmp[j] = f2bf(W[(krow + j) * stride + col]);
  uint4 o;
  o.x = (unsigned)tmp[0] | ((unsigned)tmp[1] << 16);
  o.y = (unsigned)tmp[2] | ((unsigned)tmp[3] << 16);
  o.z = (unsigned)tmp[4] | ((unsigned)tmp[5] << 16);
  o.w = (unsigned)tmp[6] | ((unsigned)tmp[7] << 16);
  reinterpret_cast<uint4*>(P)[t] = o;
}

// ---------------------------------------------------------------------------
// Flat prep: cvt x_self -> bf16 | zero deg | 22 weight-pack blocks
// ---------------------------------------------------------------------------
__global__ __launch_bounds__(256) void prep_kernel(
    const float* __restrict__ x, unsigned short* __restrict__ S1,
    int* __restrict__ deg, const float* __restrict__ Wis,
    const float* __restrict__ Wos, const float* __restrict__ Wo,
    unsigned short* __restrict__ P, int cvtB, int zeroB, int N) {
  const int blk = blockIdx.x;
  const int tid = threadIdx.x;
  if (blk < cvtB) {
    const int i = blk * 256 + tid;
    const float4 v = reinterpret_cast<const float4*>(x)[i];
    ushort4 o;
    o.x = f2bf(v.x); o.y = f2bf(v.y); o.z = f2bf(v.z); o.w = f2bf(v.w);
    reinterpret_cast<ushort4*>(S1)[i] = o;
    return;
  }
  const int b1 = blk - cvtB;
  if (b1 < zeroB) {
    const int i = b1 * 256 + tid;
    if (i < N) deg[i] = 0;
    return;
  }
  const int b = b1 - zeroB;  // 0..21
  if (b < 4)        pack_one(Wis,            P + 0,     64, 128, b * 256 + tid);
  else if (b < 8)   pack_one(Wis + 64,       P + 8192,  64, 128, (b - 4) * 256 + tid);
  else if (b < 12)  pack_one(Wos,            P + 16384, 64, 64,  (b - 8) * 256 + tid);
  else if (b < 16)  pack_one(Wos + 128 * 64, P + 24576, 64, 64,  (b - 12) * 256 + tid);
  else if (b < 20)  pack_one(Wo,             P + 32768, 64, 64,  (b - 16) * 256 + tid);
  else              pack_one(Wo + 128 * 64,  P + 40960, 64, 64,  (b - 20) * 256 + tid);
}

// ---------------------------------------------------------------------------
// deg count + W12 pack + bvec, one dispatch (independent block ranges).
// ---------------------------------------------------------------------------
__global__ __launch_bounds__(256) void deg_w12_kernel(
    const int* __restrict__ cols, int* __restrict__ deg, int E, int degB,
    const float* __restrict__ Wg1, const float* __restrict__ Wg2,
    const float* __restrict__ bg1, unsigned short* __restrict__ P12,
    float* __restrict__ bvec) {
  const int blk = blockIdx.x;
  if (blk < degB) {
    const int i = blk * 256 + threadIdx.x;
    if (i < E) atomicAdd(&deg[cols[i]], 1);
    return;
  }
  const int b = blk - degB;  // 0..32
  if (b < 32) {
    const int t = b * 256 + threadIdx.x;  // t = i*64 + j
    const int i = t >> 6, j = t & 63;
    float acc = 0.f;
    for (int k = 0; k < 128; ++k)
      acc = fmaf(Wg1[i * 128 + k], Wg2[k * 64 + j], acc);
    const int kc = i >> 5;
    const int lane = ((i >> 3) & 3) * 16 + (j & 15);
    const int jj = i & 7;
    const int ct = j >> 4;
    P12[((kc * 4 + ct) * 64 + lane) * 8 + jj] = f2bf(acc);
  } else if (threadIdx.x < 64) {
    const int j = threadIdx.x;
    float acc = 0.f;
    for (int k = 0; k < 128; ++k) acc = fmaf(bg1[k], Wg2[k * 64 + j], acc);
    bvec[j] = acc;
  }
}

// ---------------------------------------------------------------------------
// Staging helpers (16 KB / 8 KB into LDS)
// ---------------------------------------------------------------------------
__device__ __forceinline__ void stage16k(unsigned short* __restrict__ Bs,
                                         const unsigned short* __restrict__ src) {
  uint4* d = reinterpret_cast<uint4*>(Bs);
  const uint4* s = reinterpret_cast<const uint4*>(src);
  for (int i = threadIdx.x; i < 1024; i += 256) d[i] = s[i];
}

__device__ __forceinline__ void load_a_bf16(s8v a[4],
                                            const unsigned short* __restrict__ A,
                                            int arow, int koff) {
#pragma unroll
  for (int kc = 0; kc < 4; ++kc)
    a[kc] = *reinterpret_cast<const s8v*>(A + (long long)arow * 128 + kc * 32 + koff);
}

__device__ __forceinline__ void load_a_f32(s8v a[4],
                                           const float* __restrict__ A,
                                           int arow, int koff) {
#pragma unroll
  for (int kc = 0; kc < 4; ++kc) {
    const float4 f0 = *reinterpret_cast<const float4*>(
        A + (long long)arow * 128 + kc * 32 + koff);
    const float4 f1 = *reinterpret_cast<const float4*>(
        A + (long long)arow * 128 + kc * 32 + koff + 4);
    s8v r;
    r[0] = (short)f2bf(f0.x); r[1] = (short)f2bf(f0.y);
    r[2] = (short)f2bf(f0.z); r[3] = (short)f2bf(f0.w);
    r[4] = (short)f2bf(f1.x); r[5] = (short)f2bf(f1.y);
    r[6] = (short)f2bf(f1.z); r[7] = (short)f2bf(f1.w);
    a[kc] = r;
  }
}

// MFMA over one 16-KB staged panel: 4 k-chunks x 4 col-tiles
__device__ __forceinline__ void mfma_panel(f4v acc[4], const s8v a[4],
                                           const unsigned short* __restrict__ Bs,
                                           int lane) {
#pragma unroll
  for (int kc = 0; kc < 4; ++kc)
#pragma unroll
    for (int ct = 0; ct < 4; ++ct) {
      const s8v b =
          *reinterpret_cast<const s8v*>(&Bs[((kc * 4 + ct) * 64 + lane) * 8]);
      acc[ct] = __builtin_amdgcn_mfma_f32_16x16x32_bf16(a[kc], b, acc[ct], 0, 0, 0);
    }
}

// ---------------------------------------------------------------------------
// GEMM1 (2-phase cols): S2h = relu(x@Wis + bis), bf16 [N,128]. LDS 16 KB.
// ---------------------------------------------------------------------------
__device__ __forceinline__ void gemm1_body(
    unsigned short* __restrict__ Bs, const unsigned short* __restrict__ S1,
    const unsigned short* __restrict__ P, const float* __restrict__ bis,
    unsigned short* __restrict__ S2h, int blk) {
  const int tid = threadIdx.x;
  const int wave = tid >> 6, lane = tid & 63;
  const int row0 = blk * 64 + wave * 16;
  const int arow = row0 + (lane & 15);
  const int koff = (lane >> 4) * 8;
  s8v a1[4];
  load_a_bf16(a1, S1, arow, koff);
  f4v acc[8] = {};
#pragma unroll
  for (int h = 0; h < 2; ++h) {
    if (h) __syncthreads();  // all reads of previous panel done
    stage16k(Bs, P + h * 8192);
    __syncthreads();
    mfma_panel(&acc[h * 4], a1, Bs, lane);
  }
  const int crow0 = row0 + (lane >> 4) * 4;
  const int ccol = lane & 15;
#pragma unroll
  for (int h = 0; h < 2; ++h)
#pragma unroll
    for (int ctl = 0; ctl < 4; ++ctl) {
      const int col = h * 64 + ctl * 16 + ccol;
      const float bv = bis[col];
#pragma unroll
      for (int r = 0; r < 4; ++r) {
        const float v = fmaxf(acc[h * 4 + ctl][r] + bv, 0.f);
        S2h[(long long)(crow0 + r) * 128 + col] = f2bf(v);
      }
    }
}

// ---------------------------------------------------------------------------
// GEMM2 (2-phase K): out1 = x@Wos0 + h@Wos1 + bos, f32. LDS 16 KB.
// ---------------------------------------------------------------------------
__device__ __forceinline__ void gemm2_body(
    unsigned short* __restrict__ Bs, const unsigned short* __restrict__ S1,
    const unsigned short* __restrict__ S2h, const unsigned short* __restrict__ P0,
    const unsigned short* __restrict__ P1, const float* __restrict__ bos,
    float* __restrict__ out1, int blk) {
  const int tid = threadIdx.x;
  const int wave = tid >> 6, lane = tid & 63;
  const int row0 = blk * 64 + wave * 16;
  const int arow = row0 + (lane & 15);
  const int koff = (lane >> 4) * 8;
  s8v a1[4], a2[4];
  load_a_bf16(a1, S1, arow, koff);
  load_a_bf16(a2, S2h, arow, koff);
  f4v acc[4] = {};
  stage16k(Bs, P0);
  __syncthreads();
  mfma_panel(acc, a1, Bs, lane);
  __syncthreads();
  stage16k(Bs, P1);
  __syncthreads();
  mfma_panel(acc, a2, Bs, lane);
  const int crow0 = row0 + (lane >> 4) * 4;
  const int ccol = lane & 15;
#pragma unroll
  for (int ct = 0; ct < 4; ++ct) {
    const int col = ct * 16 + ccol;
    const float bv = bos[col];
#pragma unroll
    for (int r = 0; r < 4; ++r)
      out1[(long long)(crow0 + r) * 64 + col] = acc[ct][r] + bv;
  }
}

// ---------------------------------------------------------------------------
// Single-panel NC=64 GEMM (K=128 or 64). LDS = K*128 bytes.
// ---------------------------------------------------------------------------
template <int K1, bool OUT_BF16, bool A1F32, bool ACCUM>
__device__ __forceinline__ void gemm64_body(
    unsigned short* __restrict__ Bs, const void* __restrict__ A1v,
    const unsigned short* __restrict__ P1, const float* __restrict__ bias,
    void* __restrict__ Cout, int blk) {
  constexpr int KC1 = K1 / 32;
  const int tid = threadIdx.x;
  {
    uint4* d = reinterpret_cast<uint4*>(Bs);
    const uint4* s = reinterpret_cast<const uint4*>(P1);
    constexpr int n1 = K1 * 64 / 8;
    for (int i = tid; i < n1; i += 256) d[i] = s[i];
  }
  const int wave = tid >> 6, lane = tid & 63;
  const int row0 = blk * 64 + wave * 16;
  const int arow = row0 + (lane & 15);
  const int koff = (lane >> 4) * 8;
  s8v a1[KC1];
  if constexpr (A1F32) {
    const float* A1f = (const float*)A1v;
#pragma unroll
    for (int kc = 0; kc < KC1; ++kc) {
      const float4 f0 = *reinterpret_cast<const float4*>(
          A1f + (long long)arow * K1 + kc * 32 + koff);
      const float4 f1 = *reinterpret_cast<const float4*>(
          A1f + (long long)arow * K1 + kc * 32 + koff + 4);
      s8v r;
      r[0] = (short)f2bf(f0.x); r[1] = (short)f2bf(f0.y);
      r[2] = (short)f2bf(f0.z); r[3] = (short)f2bf(f0.w);
      r[4] = (short)f2bf(f1.x); r[5] = (short)f2bf(f1.y);
      r[6] = (short)f2bf(f1.z); r[7] = (short)f2bf(f1.w);
      a1[kc] = r;
    }
  } else {
    const unsigned short* A1b = (const unsigned short*)A1v;
#pragma unroll
    for (int kc = 0; kc < KC1; ++kc)
      a1[kc] = *reinterpret_cast<const s8v*>(A1b + (long long)arow * K1 +
                                             kc * 32 + koff);
  }
  __syncthreads();
  f4v acc[4] = {};
#pragma unroll
  for (int kc = 0; kc < KC1; ++kc)
#pragma unroll
    for (int ct = 0; ct < 4; ++ct) {
      const s8v b =
          *reinterpret_cast<const s8v*>(&Bs[((kc * 4 + ct) * 64 + lane) * 8]);
      acc[ct] = __builtin_amdgcn_mfma_f32_16x16x32_bf16(a1[kc], b, acc[ct], 0, 0, 0);
    }
  const int crow0 = row0 + (lane >> 4) * 4;
  const int ccol = lane & 15;
#pragma unroll
  for (int ct = 0; ct < 4; ++ct) {
    const int col = ct * 16 + ccol;
    const float bv = bias ? bias[col] : 0.f;
#pragma unroll
    for (int r = 0; r < 4; ++r) {
      const long long idx = (long long)(crow0 + r) * 64 + col;
      float v = acc[ct][r] + bv;
      if (ACCUM) v += ((float*)Cout)[idx];
      if (OUT_BF16)
        ((unsigned short*)Cout)[idx] = f2bf(v);
      else
        ((float*)Cout)[idx] = v;
    }
  }
}

// ---------------------------------------------------------------------------
// Gather body: 8 nodes/wave (8-lane groups, ushort8), 4-unroll.
// ---------------------------------------------------------------------------
template <bool PASS_B>
__device__ __forceinline__ void gather_body(
    const unsigned short* __restrict__ h, const unsigned* __restrict__ csr,
    const int* __restrict__ off, const float* __restrict__ dis,
    float* __restrict__ s_out, const float* __restrict__ s_in,
    const float* __restrict__ bvec, const float* __restrict__ bias,
    unsigned short* __restrict__ out, int N, int gb, int nblk) {
  const int wid = (gb * 256 + (int)threadIdx.x) >> 6;
  const int lane = threadIdx.x & 63;
  const int grp = lane >> 3;
  const int sl = lane & 7;
  const int stride = nblk * 32;

  float bb[8], bv[8];
  if constexpr (PASS_B) {
    const float4 b0 = *reinterpret_cast<const float4*>(bias + sl * 8);
    const float4 b1 = *reinterpret_cast<const float4*>(bias + sl * 8 + 4);
    bb[0] = b0.x; bb[1] = b0.y; bb[2] = b0.z; bb[3] = b0.w;
    bb[4] = b1.x; bb[5] = b1.y; bb[6] = b1.z; bb[7] = b1.w;
    const float4 v0 = *reinterpret_cast<const float4*>(bvec + sl * 8);
    const float4 v1 = *reinterpret_cast<const float4*>(bvec + sl * 8 + 4);
    bv[0] = v0.x; bv[1] = v0.y; bv[2] = v0.z; bv[3] = v0.w;
    bv[4] = v1.x; bv[5] = v1.y; bv[6] = v1.z; bv[7] = v1.w;
  }

  for (int n = wid * 8 + grp; n < N; n += stride) {
    const float dn = dis[n];
    const float dn2 = dn * dn;
    float a[8];
    {
      const u16x8 hv =
          *reinterpret_cast<const u16x8*>(h + (long long)n * 64 + sl * 8);
#pragma unroll
      for (int q = 0; q < 8; ++q) a[q] = bf2f(hv[q]) * dn2;
    }
    float sw = dn2;
    const int start = (n == 0) ? 0 : off[n - 1];
    const int end = off[n];
    int j = start;
    for (; j + 3 < end; j += 4) {
      const unsigned e0 = csr[j], e1 = csr[j + 1];
      const unsigned e2 = csr[j + 2], e3 = csr[j + 3];
      const u16x8 u0 = *reinterpret_cast<const u16x8*>(
          h + (long long)(e0 & 0xffffu) * 64 + sl * 8);
      const u16x8 u1 = *reinterpret_cast<const u16x8*>(
          h + (long long)(e1 & 0xffffu) * 64 + sl * 8);
      const u16x8 u2 = *reinterpret_cast<const u16x8*>(
          h + (long long)(e2 & 0xffffu) * 64 + sl * 8);
      const u16x8 u3 = *reinterpret_cast<const u16x8*>(
          h + (long long)(e3 & 0xffffu) * 64 + sl * 8);
      const float w0 = __half2float(__ushort_as_half((unsigned short)(e0 >> 16)));
      const float w1 = __half2float(__ushort_as_half((unsigned short)(e1 >> 16)));
      const float w2 = __half2float(__ushort_as_half((unsigned short)(e2 >> 16)));
      const float w3 = __half2float(__ushort_as_half((unsigned short)(e3 >> 16)));
#pragma unroll
      for (int q = 0; q < 8; ++q) {
        a[q] = fmaf(bf2f(u0[q]), w0, a[q]);
        a[q] = fmaf(bf2f(u1[q]), w1, a[q]);
        a[q] = fmaf(bf2f(u2[q]), w2, a[q]);
        a[q] = fmaf(bf2f(u3[q]), w3, a[q]);
      }
      if constexpr (!PASS_B) sw += (w0 + w1) + (w2 + w3);
    }
    for (; j < end; ++j) {
      const unsigned e = csr[j];
      const u16x8 u = *reinterpret_cast<const u16x8*>(
          h + (long long)(e & 0xffffu) * 64 + sl * 8);
      const float w = __half2float(__ushort_as_half((unsigned short)(e >> 16)));
#pragma unroll
      for (int q = 0; q < 8; ++q) a[q] = fmaf(bf2f(u[q]), w, a[q]);
      if constexpr (!PASS_B) sw += w;
    }
    u16x8 o;
    if constexpr (!PASS_B) {
      if (sl == 0) s_out[n] = sw;
#pragma unroll
      for (int q = 0; q < 8; ++q) o[q] = f2bf(a[q]);
    } else {
      const float si = s_in[n];
#pragma unroll
      for (int q = 0; q < 8; ++q) o[q] = f2bf(fmaf(si, bv[q], a[q] + bb[q]));
    }
    *reinterpret_cast<u16x8*>(out + (long long)n * 64 + sl * 8) = o;
  }
}

// ---------------------------------------------------------------------------
// CSR scan
// ---------------------------------------------------------------------------
__global__ __launch_bounds__(1024) void scan1_kernel(
    const int* __restrict__ deg, int* __restrict__ off, int* __restrict__ part,
    float* __restrict__ dis, int N) {
  __shared__ int s[1024];
  const int tid = threadIdx.x;
  const int i = blockIdx.x * 1024 + tid;
  const int v = (i < N) ? deg[i] : 0;
  if (i < N) dis[i] = rsqrtf((float)v + 1.0f);
  s[tid] = v;
  __syncthreads();
  for (int o = 1; o < 1024; o <<= 1) {
    const int t = (tid >= o) ? s[tid - o] : 0;
    __syncthreads();
    s[tid] += t;
    __syncthreads();
  }
  if (i < N) off[i] = s[tid] - v;
  if (tid == 1023) part[blockIdx.x] = s[1023];
}

__global__ __launch_bounds__(1024) void scan3_kernel(
    int* __restrict__ off, const int* __restrict__ part, int N) {
  __shared__ int pp;
  if (threadIdx.x < 64) {
    int v = (threadIdx.x < blockIdx.x) ? part[threadIdx.x] : 0;
#pragma unroll
    for (int o = 32; o > 0; o >>= 1) v += __shfl_down(v, o, 64);
    if (threadIdx.x == 0) pp = v;
  }
  __syncthreads();
  const int i = blockIdx.x * 1024 + threadIdx.x;
  if (i < N) off[i] += pp;
}

// ---------------------------------------------------------------------------
// MEGA: GEMM1 | GEMM3(x@W12) | out2a(x_nb@Wo0+bo) | fill.  LDS 16 KB.
// ---------------------------------------------------------------------------
__global__ __launch_bounds__(256) void mega_kernel(
    const unsigned short* __restrict__ S1, const float* __restrict__ x_nb,
    const unsigned short* __restrict__ P, const float* __restrict__ bis,
    const float* __restrict__ bo, unsigned short* __restrict__ S2h,
    unsigned short* __restrict__ S4, float* __restrict__ out2,
    const int* __restrict__ rows, const int* __restrict__ cols,
    int* __restrict__ off, const float* __restrict__ dis,
    unsigned* __restrict__ csr, int E, int GB) {
  __shared__ unsigned short Bs[8192];  // 16 KB
  const int b = blockIdx.x;
  if (b < GB) {
    gemm1_body(Bs, S1, P, bis, S2h, b);
  } else if (b < 2 * GB) {
    gemm64_body<128, true, false, false>(Bs, S1, P + 45056, nullptr, S4, b - GB);
  } else if (b < 3 * GB) {
    gemm64_body<128, false, true, false>(Bs, x_nb, P + 32768, bo, out2, b - 2 * GB);
  } else {
    const int i = (b - 3 * GB) * 256 + (int)threadIdx.x;
    if (i < E) {
      const int c = cols[i];
      const int r = rows[i];
      const int pos = atomicAdd(&off[c], 1);
      const unsigned wb = __half_as_ushort(__float2half(dis[r] * dis[c]));
      csr[pos] = (wb << 16) | (unsigned)r;
    }
  }
}

// ---------------------------------------------------------------------------
// G2GA: GEMM2(out1) | gatherA.  LDS 16 KB.
// ---------------------------------------------------------------------------
__global__ __launch_bounds__(256) void g2ga_kernel(
    const unsigned short* __restrict__ S1, const unsigned short* __restrict__ S2h,
    const unsigned short* __restrict__ P, const float* __restrict__ bos,
    float* __restrict__ out1, const unsigned short* __restrict__ S4,
    const unsigned* __restrict__ csr, const int* __restrict__ off,
    const float* __restrict__ dis, float* __restrict__ s_out,
    unsigned short* __restrict__ S3, int N, int GB, int GGB) {
  __shared__ unsigned short Bs[8192];  // 16 KB
  const int b = blockIdx.x;
  if (b < GB) {
    gemm2_body(Bs, S1, S2h, P + 16384, P + 24576, bos, out1, b);
  } else {
    gather_body<false>(S4, csr, off, dis, s_out, nullptr, nullptr, nullptr, S3,
                       N, b - GB, GGB);
  }
}

__global__ __launch_bounds__(256) void gatherB_kernel(
    const unsigned short* __restrict__ S3, const unsigned* __restrict__ csr,
    const int* __restrict__ off, const float* __restrict__ dis,
    const float* __restrict__ s_in, const float* __restrict__ bvec,
    const float* __restrict__ bias, unsigned short* __restrict__ G2, int N) {
  gather_body<true>(S3, csr, off, dis, nullptr, s_in, bvec, bias, G2, N,
                    blockIdx.x, gridDim.x);
}

// out2 += g2 @ Wo1   (K=64 accumulate GEMM, LDS 8 KB)
__global__ __launch_bounds__(256) void g4b_kernel(
    const unsigned short* __restrict__ G2, const unsigned short* __restrict__ P,
    float* __restrict__ out2) {
  __shared__ unsigned short Bs[4096];
  gemm64_body<64, false, false, true>(Bs, G2, P + 40960, nullptr, out2,
                                      blockIdx.x);
}

extern "C" void kernel_launch(void* const* d_in, const int* in_sizes, int n_in,
                              void* d_out, int out_size, void* d_ws,
                              size_t ws_size, hipStream_t stream) {
  const float* x_self = (const float*)d_in[0];
  const float* x_nb = (const float*)d_in[1];
  const int* ei = (const int*)d_in[2];
  const float* Wis = (const float*)d_in[3];
  const float* bis = (const float*)d_in[4];
  const float* Wos = (const float*)d_in[5];
  const float* bos = (const float*)d_in[6];
  const float* Wg1 = (const float*)d_in[7];
  const float* bg1 = (const float*)d_in[8];
  const float* Wg2 = (const float*)d_in[9];
  const float* bg2 = (const float*)d_in[10];
  const float* Wo = (const float*)d_in[11];
  const float* bo = (const float*)d_in[12];

  const int N = in_sizes[0] / 128;
  const int E = (int)(in_sizes[2] / 2);
  const int* rows = ei;
  const int* cols = ei + E;

  float* out1 = (float*)d_out;
  float* out2 = out1 + (long long)N * 64;

  // ws (4B units): dis[N] | deg[N] | off[N+16] | part[64] | s[N] | bvec[64] |
  //   csr uint[E] | S1 bf16[N*128] | S2h bf16[N*128] | S3 bf16[N*64] |
  //   S4 bf16[N*64] | P[53248]
  float* dis = (float*)d_ws;
  int* deg = (int*)(dis + N);
  int* off = deg + N;
  int* part = off + N + 16;
  float* s = (float*)(part + 64);
  float* bvec = s + N;
  unsigned* csr = (unsigned*)(bvec + 64);
  unsigned short* S1 = (unsigned short*)(csr + E);
  unsigned short* S2h = S1 + (long long)N * 128;
  unsigned short* S3 = S2h + (long long)N * 128;
  unsigned short* S4 = S3 + (long long)N * 64;
  unsigned short* P = S4 + (long long)N * 64;
  unsigned short* pW12 = P + 45056;

  const int NB = (N + 1023) / 1024;  // 40
  const int GB = N / 64;             // 625
  const int GGB = (N + 31) / 32;     // 1250

  const int cvtB = (N * 32 + 255) / 256;  // 5000
  const int zeroB = (N + 255) / 256;      // 157
  const int degB = (E + 255) / 256;       // 2500

  // 1. prep: cvt | zero deg | pack Wis(2 halves)/Wos/Wo
  prep_kernel<<<cvtB + zeroB + 22, 256, 0, stream>>>(
      x_self, S1, deg, Wis, Wos, Wo, P, cvtB, zeroB, N);
  // 2. deg count | W12 pack | bvec
  deg_w12_kernel<<<degB + 33, 256, 0, stream>>>(cols, deg, E, degB, Wg1, Wg2,
                                                bg1, pW12, bvec);
  // 3-4. scan
  scan1_kernel<<<NB, 1024, 0, stream>>>(deg, off, part, dis, N);
  scan3_kernel<<<NB, 1024, 0, stream>>>(off, part, N);
  // 5. MEGA: GEMM1 | GEMM3 | out2a | fill
  mega_kernel<<<3 * GB + degB, 256, 0, stream>>>(
      S1, x_nb, P, bis, bo, S2h, S4, out2, rows, cols, off, dis, csr, E, GB);
  // 6. GEMM2 | gatherA
  g2ga_kernel<<<GB + GGB, 256, 0, stream>>>(S1, S2h, P, bos, out1, S4, csr,
                                            off, dis, s, S3, N, GB, GGB);
  // 7. gatherB
  gatherB_kernel<<<GGB, 256, 0, stream>>>(S3, csr, off, dis, s, bvec, bg2, S1, N);
  // 8. out2 += g2 @ Wo1
  g4b_kernel<<<GB, 256, 0, stream>>>(S1, P, out2);
}